// Round 11
// baseline (1148.148 us; speedup 1.0000x reference)
//
#include <hip/hip_runtime.h>

typedef __attribute__((ext_vector_type(8))) short short8;
typedef __attribute__((ext_vector_type(4))) short s16x4;
typedef __attribute__((ext_vector_type(4))) float f32x4;
typedef unsigned short u16t;
typedef unsigned int u32t;

#define MFMA16(a,b,c) __builtin_amdgcn_mfma_f32_16x16x32_bf16((a),(b),(c),0,0,0)

__device__ __forceinline__ f32x4 mfma16x16(s16x4 a, s16x4 b, f32x4 c) {
#if __has_builtin(__builtin_amdgcn_mfma_f32_16x16x16bf16_1k)
  return __builtin_amdgcn_mfma_f32_16x16x16bf16_1k(a, b, c, 0, 0, 0);
#else
  __asm__("v_mfma_f32_16x16x16_bf16 %0, %1, %2, %0" : "+v"(c) : "v"(a), "v"(b));
  return c;
#endif
}

constexpr int Bc = 2, Nc = 2048, Dc = 1024, NHc = 16, HDc = 64;
constexpr int EStride = Nc + 80;   // E rows per head incl. zero pad

__device__ __forceinline__ u16t f2bf(float f) {   // RTN (cold paths)
  union { float f; u32t u; } v; v.f = f;
  u32t r = v.u + 0x7FFFu + ((v.u >> 16) & 1u);
  return (u16t)(r >> 16);
}
#if __has_builtin(__builtin_amdgcn_cvt_pk_bf16_f32)
__device__ __forceinline__ u32t pk2(float a, float b) {
  auto r = __builtin_amdgcn_cvt_pk_bf16_f32(a, b);
  return __builtin_bit_cast(u32t, r);
}
#else
__device__ __forceinline__ u32t pk2(float a, float b) {
  u32t ua = __builtin_bit_cast(u32t, a);
  u32t ub = __builtin_bit_cast(u32t, b);
  return ((ua + 0x8000u) >> 16) | ((ub + 0x8000u) & 0xFFFF0000u);
}
#endif
__device__ __forceinline__ s16x4 pk4(float a, float b, float c, float d) {
  union { u32t u[2]; s16x4 s; } r;
  r.u[0] = pk2(a, b); r.u[1] = pk2(c, d);
  return r.s;
}

__device__ __forceinline__ s16x4 lo4(short8 v) {
  return __builtin_shufflevector(v, v, 0, 1, 2, 3);
}
__device__ __forceinline__ s16x4 hi4(short8 v) {
  return __builtin_shufflevector(v, v, 4, 5, 6, 7);
}

// async global->LDS, 16B per lane
__device__ __forceinline__ void gld16(const u16t* g, u16t* l) {
  __builtin_amdgcn_global_load_lds(
      (const __attribute__((address_space(1))) unsigned int*)(g),
      (__attribute__((address_space(3))) unsigned int*)(l), 16, 0, 0);
}

__device__ __forceinline__ void cvt4(const float* s, u16t* d) {
  f32x4 v = *(const f32x4*)s;
  u32t* dp = (u32t*)d;
  dp[0] = pk2(v[0], v[1]); dp[1] = pk2(v[2], v[3]);
}

// Persistent-grid device barrier: monotonic counter, AGENT-scope atomics.
// Deadlock-proof: grid 768 <= resident capacity 1024 (4/CU @ 39.9KB LDS,
// VGPR<=128 via launch_bounds); bounded spin converts any logic error into
// a wrong answer instead of a hung container.
__device__ __forceinline__ void gbar(u32t* bar, u32t target) {
  __syncthreads();
  if (threadIdx.x == 0) {
    __threadfence();
    __hip_atomic_fetch_add(bar, 1u, __ATOMIC_RELEASE, __HIP_MEMORY_SCOPE_AGENT);
    u32t spins = 0;
    while (__hip_atomic_load(bar, __ATOMIC_ACQUIRE, __HIP_MEMORY_SCOPE_AGENT) <
               target && ++spins < 100000000u)
      __builtin_amdgcn_s_sleep(8);
    __threadfence();
  }
  __syncthreads();
}

// ======================= FUSED persistent kernel =======================
// 4 phases, one launch; 3 device barriers replace 3 inter-kernel gaps
// (accounting r0-r9: non-attn time invariant ~134us while qkv=38.5 [r6<->r8
// isolation], cvt~10 [60MB stream], proj<=20 [roofline + occupancy-neutral]
// -> ~60-70us is launch/drain overhead). No cooperative API (r10 lesson:
// hipLaunchCooperativeKernel + graph capture killed the container twice).
__global__ __launch_bounds__(256, 4) void fused(
    const float* __restrict__ x, const float* __restrict__ wq,
    const float* __restrict__ wk, const float* __restrict__ wv,
    const float* __restrict__ wp, const float* __restrict__ bp,
    const float* __restrict__ rel, float* __restrict__ out,
    u16t* __restrict__ xb, u16t* __restrict__ wqb, u16t* __restrict__ wkb,
    u16t* __restrict__ wvb, u16t* __restrict__ wpb, u16t* __restrict__ Eb,
    u16t* __restrict__ Qb, u16t* __restrict__ Kb, u16t* __restrict__ Vt,
    u16t* __restrict__ AO, u32t* __restrict__ ctr) {
  __shared__ __align__(16) u16t lE[128 * 72];      // 18432 B (aliased)
  __shared__ __align__(16) float Ps[4][16 * 84];   // 21504 B (aliased)
  __shared__ u32t sTau;

  const int bid = blockIdx.x;
  const int t = threadIdx.x, wave = t >> 6, lane = t & 63;
  const int l15 = lane & 15, q4 = lane >> 4;

  // ---------------- phase 0: conversions (grid-stride, 768 blocks) ------
  for (int i = bid * 256 + t; i < 2641920; i += 196608) {
    if (i < 1048576) {                        // x
      cvt4(x + (size_t)i * 4, xb + (size_t)i * 4);
    } else if (i < 2097152) {                 // weights
      int r = i - 1048576;
      int w = r >> 18;
      int k = (r & 262143) * 4;
      const float* s = (w == 0) ? wq : (w == 1) ? wk : (w == 2) ? wv : wp;
      u16t* d = (w == 0) ? wqb : (w == 1) ? wkb : (w == 2) ? wvb : wpb;
      cvt4(s + k, d + k);
    } else if (i < 2621440) {                 // E remap to [h][m][hd]
      int r = i - 2097152;
      int flat = r * 4;
      int h = flat >> 17;
      int rem = flat & 131071;
      int m = rem >> 6, d = rem & 63;
      cvt4(rel + (size_t)m * Dc + h * HDc + d,
           Eb + ((size_t)h * EStride + m) * HDc + d);
    } else {                                  // zero pad rows [Nc, Nc+80)
      int r = i - 2621440;
      int flat = r * 4;
      int h = flat / 5120;
      int rem = flat - h * 5120;
      int pr = rem >> 6, d = rem & 63;
      u32t* dp = (u32t*)(Eb + ((size_t)h * EStride + Nc + pr) * HDc + d);
      dp[0] = 0; dp[1] = 0;
    }
  }
  gbar(ctr, 768u);

  // ---------------- phase 1: QKV GEMM (768 blocks, r6 structure 1:1) ----
  {
    u16t* lA = lE;                    // 8192 B
    u16t* lB = (u16t*)&Ps[0][0];      // 8192 B
    const int bx = bid & 31, y = bid >> 5, which = y >> 3;
    const u16t* W = (which == 0) ? wqb : (which == 1) ? wkb : wvb;
    const float sc = 0.18033688011112042f;    // Q only
    const int m0 = bx * 128, n0 = (y & 7) * 128;
    const int wm = wave & 1, wn = wave >> 1;
    const int srow = wave * 16 + (lane >> 2);
    const int scol = (lane & 3) * 8;

    f32x4 acc[4][4];
    for (int i = 0; i < 4; i++)
      for (int j = 0; j < 4; j++)
        for (int r = 0; r < 4; r++) acc[i][j][r] = 0.f;

    for (int k0 = 0; k0 < Dc; k0 += 32) {
      __syncthreads();
      for (int r = 0; r < 2; r++) {
        int row = srow + r * 64;
        gld16(xb + (size_t)(m0 + row) * Dc + k0 + scol, lA + wave * 512 + r * 2048);
        gld16(W + (size_t)(n0 + row) * Dc + k0 + scol, lB + wave * 512 + r * 2048);
      }
      __syncthreads();
      short8 af[4], bf[4];
      for (int i = 0; i < 4; i++) {
        af[i] = *(const short8*)(&lA[(wm * 64 + i * 16 + l15) * 32 + q4 * 8]);
        bf[i] = *(const short8*)(&lB[(wn * 64 + i * 16 + l15) * 32 + q4 * 8]);
      }
      for (int mi = 0; mi < 4; mi++)
        for (int ni = 0; ni < 4; ni++)
          acc[mi][ni] = MFMA16(af[mi], bf[ni], acc[mi][ni]);
    }

    if (which == 0) {
      for (int mi = 0; mi < 4; mi++)
        for (int ni = 0; ni < 4; ni++)
          for (int rg = 0; rg < 4; rg++) {
            int gm = m0 + wm * 64 + mi * 16 + q4 * 4 + rg;
            int gn = n0 + wn * 64 + ni * 16 + l15;
            int b = gm >> 11, n = gm & 2047, h = gn >> 6, hd = gn & 63;
            Qb[(((size_t)(b * NHc + h) * Nc + n) * HDc) + hd] =
                f2bf(acc[mi][ni][rg] * sc);
          }
    } else if (which == 1) {
      for (int mi = 0; mi < 4; mi++)
        for (int ni = 0; ni < 4; ni++)
          for (int rg = 0; rg < 4; rg++) {
            int gm = m0 + wm * 64 + mi * 16 + q4 * 4 + rg;
            int gn = n0 + wn * 64 + ni * 16 + l15;
            int b = gm >> 11, n = gm & 2047, h = gn >> 6, hd = gn & 63;
            size_t off = (size_t)(b * NHc + h) * Nc * HDc
                       + (size_t)(n >> 6) * 4096
                       + ((((n >> 4) & 3) * 2 + (hd >> 5)) * 512)
                       + (((hd >> 3) & 3) * 128) + ((n & 15) * 8) + (hd & 7);
            Kb[off] = f2bf(acc[mi][ni][rg]);
          }
    } else {
      for (int mi = 0; mi < 4; mi++)
        for (int ni = 0; ni < 4; ni++) {
          int gm = m0 + wm * 64 + mi * 16 + q4 * 4;       // n base (rg=0)
          int gn = n0 + wn * 64 + ni * 16 + l15;
          int b = gm >> 11, n = gm & 2047, h = gn >> 6, hd = gn & 63;
          s16x4 pkv = pk4(acc[mi][ni][0], acc[mi][ni][1],
                          acc[mi][ni][2], acc[mi][ni][3]);
          size_t off = (size_t)(b * NHc + h) * Nc * HDc
                     + (size_t)(n >> 6) * 4096
                     + (((hd >> 4) * 2 + ((n >> 5) & 1)) * 512)
                     + (((n >> 2) & 3) * 128) + ((hd & 15) * 8)
                     + (((n >> 4) & 1) * 4);
          *(s16x4*)(&Vt[off]) = pkv;
        }
    }
  }
  gbar(ctr, 1536u);

  // ---------------- phase 2: attn (r2 dbuf body, atomic work ticket) ----
  // Ticket order tau -> qi = 31-(tau>>5): longest-first + true backfill.
  {
    const int tbase = (3 - wave) * 16;
    const int Tm = wave * 16 + l15;
    float* Pw = Ps[wave];
    const int sr = t >> 3, sc8 = (t & 7) * 8;
    const int sr2 = sr + 32;

    for (;;) {
      if (t == 0) sTau = atomicAdd(&ctr[1], 1u);
      __syncthreads();               // broadcast + guards lE/Ps vs prev tile
      u32t tau = sTau;
      if (tau >= 1024u) break;
      const int qi = 31 - ((int)tau >> 5);
      const int bh = (int)tau & 31;
      const int b = bh >> 4, h = bh & 15;
      const u16t* Qh = Qb + (size_t)(b * NHc + h) * Nc * HDc;
      const u16t* Kh = Kb + (size_t)(b * NHc + h) * Nc * HDc;  // frag layout
      const u16t* Vh = Vt + (size_t)(b * NHc + h) * Nc * HDc;  // frag layout
      const u16t* Eh = Eb + (size_t)h * EStride * HDc;
      const int r0 = qi * 64;
      const int rw = r0 + wave * 16;
      const int ebase0 = Nc - 63 - r0;

      short8 qf[2], qsf[2];
      {
        int r = rw + l15;
        int rs = r - 1; if (rs < 0) rs = 0;
        for (int kh = 0; kh < 2; kh++) {
          qf[kh]  = *(const short8*)(Qh + (size_t)r * HDc + kh * 32 + q4 * 8);
          qsf[kh] = *(const short8*)(Qh + (size_t)rs * HDc + kh * 32 + q4 * 8);
        }
      }

      f32x4 accO[4];
      f32x4 l4;
      for (int rg = 0; rg < 4; rg++) l4[rg] = 0.f;
      for (int dt = 0; dt < 4; dt++)
        for (int rg = 0; rg < 4; rg++) accO[dt][rg] = 0.f;

      short8 kf[8];
#pragma unroll
      for (int i = 0; i < 8; i++)
        kf[i] = *(const short8*)(Kh + i * 512 + lane * 8);

      auto body = [&](int j, bool last, bool pf) {
        const u16t* Vj = Vh + (size_t)j * 4096;
        short8 vf[8];
#pragma unroll
        for (int i = 0; i < 8; i++)
          vf[i] = *(const short8*)(Vj + i * 512 + lane * 8);

        f32x4 accS[4];
        for (int ct = 0; ct < 4; ct++)
          for (int rg = 0; rg < 4; rg++) accS[ct][rg] = 0.f;
#pragma unroll
        for (int kh = 0; kh < 2; kh++)
#pragma unroll
          for (int ct = 0; ct < 4; ct++)
            accS[ct] = MFMA16(kf[ct * 2 + kh], qf[kh], accS[ct]);

        if (pf) {
          const u16t* Kn = Kh + (size_t)(j + 1) * 4096;
#pragma unroll
          for (int i = 0; i < 8; i++)
            kf[i] = *(const short8*)(Kn + i * 512 + lane * 8);
        }

        const int rot = (j & 1) << 6;
        const int pb = tbase + l15 + rot;
#pragma unroll
        for (int pt = 0; pt < 5; pt++) {
          int pr = (pb + pt * 16) & 127;
          f32x4 ap;
          ap[0] = 0.f; ap[1] = 0.f; ap[2] = 0.f; ap[3] = 0.f;
#pragma unroll
          for (int kh = 0; kh < 2; kh++) {
            short8 efr = *(const short8*)(&lE[pr * 72 + kh * 32 + q4 * 8]);
            ap = MFMA16(efr, qsf[kh], ap);
          }
          *(f32x4*)(&Pw[l15 * 84 + pt * 16 + q4 * 4]) = ap;
        }

        __asm__ volatile("s_waitcnt lgkmcnt(0)" ::: "memory");
        __builtin_amdgcn_sched_barrier(0);
        const int rbase = l15 * 83 + q4 * 4 + 15;
        s16x4 bq[4];
#pragma unroll
        for (int ct = 0; ct < 4; ct++) {
          float pv[4];
#pragma unroll
          for (int rg = 0; rg < 4; rg++) {
            float s = accS[ct][rg] + Pw[rbase + ct * 16 + rg];
            if (last && (ct * 16 + q4 * 4 + rg) > Tm) s = -1e30f;
            float p = exp2f(s);
            l4[rg] += p;
            pv[rg] = p;
          }
          bq[ct] = pk4(pv[0], pv[1], pv[2], pv[3]);
        }
        __asm__ volatile("" ::: "memory");
#pragma unroll
        for (int dt = 0; dt < 4; dt++)
#pragma unroll
          for (int ks = 0; ks < 4; ks++) {
            s16x4 vfr = (ks & 1) ? hi4(vf[dt * 2 + (ks >> 1)])
                                 : lo4(vf[dt * 2 + (ks >> 1)]);
            accO[dt] = mfma16x16(vfr, bq[ks], accO[dt]);
          }
      };

      // init lE phys [0,128) = E rows ebase0+[0,128)
      for (int i = 0; i < 4; i++) {
        int cc = t + i * 256;
        int s = cc >> 3, c8 = (cc & 7) * 8;
        *(f32x4*)(&lE[s * 72 + c8]) =
            *(const f32x4*)(Eh + (size_t)(ebase0 + s) * HDc + c8);
      }

      for (int j = 0; j < qi; j++) {
        __syncthreads();
        const int ebn = ebase0 + 64 * j + 128;     // chunk for step j+1
        f32x4 pE0 = *(const f32x4*)(Eh + (size_t)(ebn + sr) * HDc + sc8);
        f32x4 pE1 = *(const f32x4*)(Eh + (size_t)(ebn + sr2) * HDc + sc8);
        body(j, false, true);
        __syncthreads();
        int ph0 = (sr + 64 * j) & 127;
        int ph1 = (sr2 + 64 * j) & 127;
        *(f32x4*)(&lE[ph0 * 72 + sc8]) = pE0;
        *(f32x4*)(&lE[ph1 * 72 + sc8]) = pE1;
      }
      __syncthreads();
      body(qi, true, false);

      float l_p = (l4[0] + l4[1]) + (l4[2] + l4[3]);
      float l2 = l_p + __shfl_xor(l_p, 16);
      float lt = l2 + __shfl_xor(l2, 32);
      float inv = 1.f / lt;
      {
        int r = rw + l15;
        u16t* dst = AO + (size_t)(b * Nc + r) * Dc + h * HDc + q4 * 4;
        for (int dt = 0; dt < 4; dt++) {
          s16x4 o = pk4(accO[dt][0] * inv, accO[dt][1] * inv,
                        accO[dt][2] * inv, accO[dt][3] * inv);
          *(s16x4*)(dst + dt * 16) = o;
        }
      }
    }
  }
  gbar(ctr, 2304u);

  // ---------------- phase 3: output projection (r9 64x64, grid-stride) ---
  for (int pb = bid; pb < 1024; pb += 768) {
    u16t* pA = lE;                    // 4096 B
    u16t* pB = (u16t*)&Ps[0][0];      // 4096 B
    const int m0 = (pb & 63) * 64, n0 = (pb >> 6) * 64;
    const int wm = wave & 1, wn = wave >> 1;
    const int srow = t >> 2;
    const int scol = (t & 3) * 8;

    f32x4 acc[2][2];
    for (int i = 0; i < 2; i++)
      for (int j = 0; j < 2; j++)
        for (int r = 0; r < 4; r++) acc[i][j][r] = 0.f;

    for (int k0 = 0; k0 < Dc; k0 += 32) {
      __syncthreads();
      gld16(AO + (size_t)(m0 + srow) * Dc + k0 + scol, pA + wave * 512);
      gld16(wpb + (size_t)(n0 + srow) * Dc + k0 + scol, pB + wave * 512);
      __syncthreads();
      short8 af[2], bf[2];
      for (int i = 0; i < 2; i++) {
        af[i] = *(const short8*)(&pA[(wm * 32 + i * 16 + l15) * 32 + q4 * 8]);
        bf[i] = *(const short8*)(&pB[(wn * 32 + i * 16 + l15) * 32 + q4 * 8]);
      }
      for (int mi = 0; mi < 2; mi++)
        for (int ni = 0; ni < 2; ni++)
          acc[mi][ni] = MFMA16(af[mi], bf[ni], acc[mi][ni]);
    }

    for (int mi = 0; mi < 2; mi++)
      for (int ni = 0; ni < 2; ni++)
        for (int rg = 0; rg < 4; rg++) {
          int gm = m0 + wm * 32 + mi * 16 + q4 * 4 + rg;
          int gn = n0 + wn * 32 + ni * 16 + l15;
          out[(size_t)gm * Dc + gn] = acc[mi][ni][rg] + bp[gn];
        }
    __syncthreads();   // guard pA/pB reuse across grid-stride iterations
  }
}

// ---------------- host ----------------
extern "C" void kernel_launch(void* const* d_in, const int* in_sizes, int n_in,
                              void* d_out, int out_size, void* d_ws, size_t ws_size,
                              hipStream_t stream) {
  (void)in_sizes; (void)n_in; (void)out_size; (void)ws_size;
  const float* x   = (const float*)d_in[0];
  const float* Wq  = (const float*)d_in[1];
  const float* Wk  = (const float*)d_in[2];
  const float* Wv  = (const float*)d_in[3];
  const float* Wp  = (const float*)d_in[4];
  const float* bp  = (const float*)d_in[5];
  const float* rel = (const float*)d_in[6];
  float* out = (float*)d_out;

  char* ws = (char*)d_ws;
  u16t* xb  = (u16t*)(ws);
  u16t* wqb = (u16t*)(ws + 8388608);
  u16t* wkb = (u16t*)(ws + 10485760);
  u16t* wvb = (u16t*)(ws + 12582912);
  u16t* wpb = (u16t*)(ws + 14680064);
  u16t* Eb  = (u16t*)(ws + 16777216);   // 16*2128*64*2 = 4358144 B
  u16t* Qb  = (u16t*)(ws + 21233664);
  u16t* Kb  = (u16t*)(ws + 29622272);
  u16t* Vtb = (u16t*)(ws + 38010880);
  u16t* AOb = (u16t*)(ws + 46399488);   // ends at 54788096
  u32t* ctr = (u32t*)(ws + 54788096);   // [0]=barrier, [1]=attn ticket

  hipMemsetAsync(ctr, 0, 16, stream);   // graph-capturable (harness uses it)
  fused<<<dim3(768), dim3(256), 0, stream>>>(
      x, Wq, Wk, Wv, Wp, bp, rel, out,
      xb, wqb, wkb, wvb, wpb, Eb, Qb, Kb, Vtb, AOb, ctr);
}

// Round 12
// 693.121 us; speedup vs baseline: 1.6565x; 1.6565x over previous
//
#include <hip/hip_runtime.h>

typedef __attribute__((ext_vector_type(8))) short short8;
typedef __attribute__((ext_vector_type(4))) short s16x4;
typedef __attribute__((ext_vector_type(4))) float f32x4;
typedef unsigned short u16t;
typedef unsigned int u32t;

#define MFMA16(a,b,c) __builtin_amdgcn_mfma_f32_16x16x32_bf16((a),(b),(c),0,0,0)

__device__ __forceinline__ f32x4 mfma16x16(s16x4 a, s16x4 b, f32x4 c) {
#if __has_builtin(__builtin_amdgcn_mfma_f32_16x16x16bf16_1k)
  return __builtin_amdgcn_mfma_f32_16x16x16bf16_1k(a, b, c, 0, 0, 0);
#else
  __asm__("v_mfma_f32_16x16x16_bf16 %0, %1, %2, %0" : "+v"(c) : "v"(a), "v"(b));
  return c;
#endif
}

constexpr int Bc = 2, Nc = 2048, Dc = 1024, NHc = 16, HDc = 64;
constexpr int EStride = Nc + 80;   // E rows per head incl. zero pad

__device__ __forceinline__ u16t f2bf(float f) {   // RTN (cold paths)
  union { float f; u32t u; } v; v.f = f;
  u32t r = v.u + 0x7FFFu + ((v.u >> 16) & 1u);
  return (u16t)(r >> 16);
}
#if __has_builtin(__builtin_amdgcn_cvt_pk_bf16_f32)
__device__ __forceinline__ u32t pk2(float a, float b) {
  auto r = __builtin_amdgcn_cvt_pk_bf16_f32(a, b);
  return __builtin_bit_cast(u32t, r);
}
#else
__device__ __forceinline__ u32t pk2(float a, float b) {
  u32t ua = __builtin_bit_cast(u32t, a);
  u32t ub = __builtin_bit_cast(u32t, b);
  return ((ua + 0x8000u) >> 16) | ((ub + 0x8000u) & 0xFFFF0000u);
}
#endif
__device__ __forceinline__ s16x4 pk4(float a, float b, float c, float d) {
  union { u32t u[2]; s16x4 s; } r;
  r.u[0] = pk2(a, b); r.u[1] = pk2(c, d);
  return r.s;
}

__device__ __forceinline__ s16x4 lo4(short8 v) {
  return __builtin_shufflevector(v, v, 0, 1, 2, 3);
}
__device__ __forceinline__ s16x4 hi4(short8 v) {
  return __builtin_shufflevector(v, v, 4, 5, 6, 7);
}

// async global->LDS, 16B per lane
__device__ __forceinline__ void gld16(const u16t* g, u16t* l) {
  __builtin_amdgcn_global_load_lds(
      (const __attribute__((address_space(1))) unsigned int*)(g),
      (__attribute__((address_space(3))) unsigned int*)(l), 16, 0, 0);
}

__device__ __forceinline__ void cvt4(const float* s, u16t* d) {
  f32x4 v = *(const f32x4*)s;
  u32t* dp = (u32t*)d;
  dp[0] = pk2(v[0], v[1]); dp[1] = pk2(v[2], v[3]);
}

// Persistent-grid device barrier, v2 (r11 post-mortem).
// r11's version spun with ACQUIRE agent-scope loads every ~512cy: each
// acquire emits cache-maintenance -> waiting blocks continuously invalidated
// their XCD's L2, evicting the working blocks' tiles (FETCH 361MB / WRITE
// 480MB, 750GB/s, dur fully traffic-explained). v2: RELAXED spin loads
// (plain sc1 load, no inv) polled every ~1.7us; ordering hoisted to ONE
// __threadfence release before the add + ONE acquire after the spin --
// semantically equal to r11 (which PASSED correctness), cache maintenance
// once per barrier instead of per iteration. Deadlock-proof: grid 768 <=
// capacity; bounded spin -> wrong answer, not a hung container.
__device__ __forceinline__ void gbar(u32t* bar, u32t target) {
  __syncthreads();
  if (threadIdx.x == 0) {
    __threadfence();   // release: this phase's writes visible device-wide
    __hip_atomic_fetch_add(bar, 1u, __ATOMIC_RELAXED, __HIP_MEMORY_SCOPE_AGENT);
    u32t spins = 0;
    while (__hip_atomic_load(bar, __ATOMIC_RELAXED, __HIP_MEMORY_SCOPE_AGENT) <
               target && ++spins < 2000000u)
      __builtin_amdgcn_s_sleep(64);
    __threadfence();   // acquire: drop stale lines before reading peers' data
  }
  __syncthreads();
}

// ======================= FUSED persistent kernel =======================
// 4 phases, one launch; 3 device barriers replace 3 inter-kernel gaps
// (accounting r0-r9: non-attn time invariant ~134us while qkv=38.5, cvt~10,
// proj<=20 -> ~60-70us launch/drain overhead). Phases byte-identical to r11
// (hardware-verified correct); only the barrier spin changed.
__global__ __launch_bounds__(256, 4) void fused(
    const float* __restrict__ x, const float* __restrict__ wq,
    const float* __restrict__ wk, const float* __restrict__ wv,
    const float* __restrict__ wp, const float* __restrict__ bp,
    const float* __restrict__ rel, float* __restrict__ out,
    u16t* __restrict__ xb, u16t* __restrict__ wqb, u16t* __restrict__ wkb,
    u16t* __restrict__ wvb, u16t* __restrict__ wpb, u16t* __restrict__ Eb,
    u16t* __restrict__ Qb, u16t* __restrict__ Kb, u16t* __restrict__ Vt,
    u16t* __restrict__ AO, u32t* __restrict__ ctr) {
  __shared__ __align__(16) u16t lE[128 * 72];      // 18432 B (aliased)
  __shared__ __align__(16) float Ps[4][16 * 84];   // 21504 B (aliased)
  __shared__ u32t sTau;

  const int bid = blockIdx.x;
  const int t = threadIdx.x, wave = t >> 6, lane = t & 63;
  const int l15 = lane & 15, q4 = lane >> 4;

  // ---------------- phase 0: conversions (grid-stride, 768 blocks) ------
  for (int i = bid * 256 + t; i < 2641920; i += 196608) {
    if (i < 1048576) {                        // x
      cvt4(x + (size_t)i * 4, xb + (size_t)i * 4);
    } else if (i < 2097152) {                 // weights
      int r = i - 1048576;
      int w = r >> 18;
      int k = (r & 262143) * 4;
      const float* s = (w == 0) ? wq : (w == 1) ? wk : (w == 2) ? wv : wp;
      u16t* d = (w == 0) ? wqb : (w == 1) ? wkb : (w == 2) ? wvb : wpb;
      cvt4(s + k, d + k);
    } else if (i < 2621440) {                 // E remap to [h][m][hd]
      int r = i - 2097152;
      int flat = r * 4;
      int h = flat >> 17;
      int rem = flat & 131071;
      int m = rem >> 6, d = rem & 63;
      cvt4(rel + (size_t)m * Dc + h * HDc + d,
           Eb + ((size_t)h * EStride + m) * HDc + d);
    } else {                                  // zero pad rows [Nc, Nc+80)
      int r = i - 2621440;
      int flat = r * 4;
      int h = flat / 5120;
      int rem = flat - h * 5120;
      int pr = rem >> 6, d = rem & 63;
      u32t* dp = (u32t*)(Eb + ((size_t)h * EStride + Nc + pr) * HDc + d);
      dp[0] = 0; dp[1] = 0;
    }
  }
  gbar(ctr, 768u);

  // ---------------- phase 1: QKV GEMM (768 blocks, r6 structure 1:1) ----
  {
    u16t* lA = lE;                    // 8192 B
    u16t* lB = (u16t*)&Ps[0][0];      // 8192 B
    const int bx = bid & 31, y = bid >> 5, which = y >> 3;
    const u16t* W = (which == 0) ? wqb : (which == 1) ? wkb : wvb;
    const float sc = 0.18033688011112042f;    // Q only
    const int m0 = bx * 128, n0 = (y & 7) * 128;
    const int wm = wave & 1, wn = wave >> 1;
    const int srow = wave * 16 + (lane >> 2);
    const int scol = (lane & 3) * 8;

    f32x4 acc[4][4];
    for (int i = 0; i < 4; i++)
      for (int j = 0; j < 4; j++)
        for (int r = 0; r < 4; r++) acc[i][j][r] = 0.f;

    for (int k0 = 0; k0 < Dc; k0 += 32) {
      __syncthreads();
      for (int r = 0; r < 2; r++) {
        int row = srow + r * 64;
        gld16(xb + (size_t)(m0 + row) * Dc + k0 + scol, lA + wave * 512 + r * 2048);
        gld16(W + (size_t)(n0 + row) * Dc + k0 + scol, lB + wave * 512 + r * 2048);
      }
      __syncthreads();
      short8 af[4], bf[4];
      for (int i = 0; i < 4; i++) {
        af[i] = *(const short8*)(&lA[(wm * 64 + i * 16 + l15) * 32 + q4 * 8]);
        bf[i] = *(const short8*)(&lB[(wn * 64 + i * 16 + l15) * 32 + q4 * 8]);
      }
      for (int mi = 0; mi < 4; mi++)
        for (int ni = 0; ni < 4; ni++)
          acc[mi][ni] = MFMA16(af[mi], bf[ni], acc[mi][ni]);
    }

    if (which == 0) {
      for (int mi = 0; mi < 4; mi++)
        for (int ni = 0; ni < 4; ni++)
          for (int rg = 0; rg < 4; rg++) {
            int gm = m0 + wm * 64 + mi * 16 + q4 * 4 + rg;
            int gn = n0 + wn * 64 + ni * 16 + l15;
            int b = gm >> 11, n = gm & 2047, h = gn >> 6, hd = gn & 63;
            Qb[(((size_t)(b * NHc + h) * Nc + n) * HDc) + hd] =
                f2bf(acc[mi][ni][rg] * sc);
          }
    } else if (which == 1) {
      for (int mi = 0; mi < 4; mi++)
        for (int ni = 0; ni < 4; ni++)
          for (int rg = 0; rg < 4; rg++) {
            int gm = m0 + wm * 64 + mi * 16 + q4 * 4 + rg;
            int gn = n0 + wn * 64 + ni * 16 + l15;
            int b = gm >> 11, n = gm & 2047, h = gn >> 6, hd = gn & 63;
            size_t off = (size_t)(b * NHc + h) * Nc * HDc
                       + (size_t)(n >> 6) * 4096
                       + ((((n >> 4) & 3) * 2 + (hd >> 5)) * 512)
                       + (((hd >> 3) & 3) * 128) + ((n & 15) * 8) + (hd & 7);
            Kb[off] = f2bf(acc[mi][ni][rg]);
          }
    } else {
      for (int mi = 0; mi < 4; mi++)
        for (int ni = 0; ni < 4; ni++) {
          int gm = m0 + wm * 64 + mi * 16 + q4 * 4;       // n base (rg=0)
          int gn = n0 + wn * 64 + ni * 16 + l15;
          int b = gm >> 11, n = gm & 2047, h = gn >> 6, hd = gn & 63;
          s16x4 pkv = pk4(acc[mi][ni][0], acc[mi][ni][1],
                          acc[mi][ni][2], acc[mi][ni][3]);
          size_t off = (size_t)(b * NHc + h) * Nc * HDc
                     + (size_t)(n >> 6) * 4096
                     + (((hd >> 4) * 2 + ((n >> 5) & 1)) * 512)
                     + (((n >> 2) & 3) * 128) + ((hd & 15) * 8)
                     + (((n >> 4) & 1) * 4);
          *(s16x4*)(&Vt[off]) = pkv;
        }
    }
  }
  gbar(ctr, 1536u);

  // ---------------- phase 2: attn (r2 dbuf body, atomic work ticket) ----
  // Ticket order tau -> qi = 31-(tau>>5): longest-first + true backfill.
  {
    const int tbase = (3 - wave) * 16;
    const int Tm = wave * 16 + l15;
    float* Pw = Ps[wave];
    const int sr = t >> 3, sc8 = (t & 7) * 8;
    const int sr2 = sr + 32;

    for (;;) {
      if (t == 0) sTau = atomicAdd(&ctr[1], 1u);
      __syncthreads();               // broadcast + guards lE/Ps vs prev tile
      u32t tau = sTau;
      if (tau >= 1024u) break;
      const int qi = 31 - ((int)tau >> 5);
      const int bh = (int)tau & 31;
      const int b = bh >> 4, h = bh & 15;
      const u16t* Qh = Qb + (size_t)(b * NHc + h) * Nc * HDc;
      const u16t* Kh = Kb + (size_t)(b * NHc + h) * Nc * HDc;  // frag layout
      const u16t* Vh = Vt + (size_t)(b * NHc + h) * Nc * HDc;  // frag layout
      const u16t* Eh = Eb + (size_t)h * EStride * HDc;
      const int r0 = qi * 64;
      const int rw = r0 + wave * 16;
      const int ebase0 = Nc - 63 - r0;

      short8 qf[2], qsf[2];
      {
        int r = rw + l15;
        int rs = r - 1; if (rs < 0) rs = 0;
        for (int kh = 0; kh < 2; kh++) {
          qf[kh]  = *(const short8*)(Qh + (size_t)r * HDc + kh * 32 + q4 * 8);
          qsf[kh] = *(const short8*)(Qh + (size_t)rs * HDc + kh * 32 + q4 * 8);
        }
      }

      f32x4 accO[4];
      f32x4 l4;
      for (int rg = 0; rg < 4; rg++) l4[rg] = 0.f;
      for (int dt = 0; dt < 4; dt++)
        for (int rg = 0; rg < 4; rg++) accO[dt][rg] = 0.f;

      short8 kf[8];
#pragma unroll
      for (int i = 0; i < 8; i++)
        kf[i] = *(const short8*)(Kh + i * 512 + lane * 8);

      auto body = [&](int j, bool last, bool pf) {
        const u16t* Vj = Vh + (size_t)j * 4096;
        short8 vf[8];
#pragma unroll
        for (int i = 0; i < 8; i++)
          vf[i] = *(const short8*)(Vj + i * 512 + lane * 8);

        f32x4 accS[4];
        for (int ct = 0; ct < 4; ct++)
          for (int rg = 0; rg < 4; rg++) accS[ct][rg] = 0.f;
#pragma unroll
        for (int kh = 0; kh < 2; kh++)
#pragma unroll
          for (int ct = 0; ct < 4; ct++)
            accS[ct] = MFMA16(kf[ct * 2 + kh], qf[kh], accS[ct]);

        if (pf) {
          const u16t* Kn = Kh + (size_t)(j + 1) * 4096;
#pragma unroll
          for (int i = 0; i < 8; i++)
            kf[i] = *(const short8*)(Kn + i * 512 + lane * 8);
        }

        const int rot = (j & 1) << 6;
        const int pb = tbase + l15 + rot;
#pragma unroll
        for (int pt = 0; pt < 5; pt++) {
          int pr = (pb + pt * 16) & 127;
          f32x4 ap;
          ap[0] = 0.f; ap[1] = 0.f; ap[2] = 0.f; ap[3] = 0.f;
#pragma unroll
          for (int kh = 0; kh < 2; kh++) {
            short8 efr = *(const short8*)(&lE[pr * 72 + kh * 32 + q4 * 8]);
            ap = MFMA16(efr, qsf[kh], ap);
          }
          *(f32x4*)(&Pw[l15 * 84 + pt * 16 + q4 * 4]) = ap;
        }

        __asm__ volatile("s_waitcnt lgkmcnt(0)" ::: "memory");
        __builtin_amdgcn_sched_barrier(0);
        const int rbase = l15 * 83 + q4 * 4 + 15;
        s16x4 bq[4];
#pragma unroll
        for (int ct = 0; ct < 4; ct++) {
          float pv[4];
#pragma unroll
          for (int rg = 0; rg < 4; rg++) {
            float s = accS[ct][rg] + Pw[rbase + ct * 16 + rg];
            if (last && (ct * 16 + q4 * 4 + rg) > Tm) s = -1e30f;
            float p = exp2f(s);
            l4[rg] += p;
            pv[rg] = p;
          }
          bq[ct] = pk4(pv[0], pv[1], pv[2], pv[3]);
        }
        __asm__ volatile("" ::: "memory");
#pragma unroll
        for (int dt = 0; dt < 4; dt++)
#pragma unroll
          for (int ks = 0; ks < 4; ks++) {
            s16x4 vfr = (ks & 1) ? hi4(vf[dt * 2 + (ks >> 1)])
                                 : lo4(vf[dt * 2 + (ks >> 1)]);
            accO[dt] = mfma16x16(vfr, bq[ks], accO[dt]);
          }
      };

      // init lE phys [0,128) = E rows ebase0+[0,128)
      for (int i = 0; i < 4; i++) {
        int cc = t + i * 256;
        int s = cc >> 3, c8 = (cc & 7) * 8;
        *(f32x4*)(&lE[s * 72 + c8]) =
            *(const f32x4*)(Eh + (size_t)(ebase0 + s) * HDc + c8);
      }

      for (int j = 0; j < qi; j++) {
        __syncthreads();
        const int ebn = ebase0 + 64 * j + 128;     // chunk for step j+1
        f32x4 pE0 = *(const f32x4*)(Eh + (size_t)(ebn + sr) * HDc + sc8);
        f32x4 pE1 = *(const f32x4*)(Eh + (size_t)(ebn + sr2) * HDc + sc8);
        body(j, false, true);
        __syncthreads();
        int ph0 = (sr + 64 * j) & 127;
        int ph1 = (sr2 + 64 * j) & 127;
        *(f32x4*)(&lE[ph0 * 72 + sc8]) = pE0;
        *(f32x4*)(&lE[ph1 * 72 + sc8]) = pE1;
      }
      __syncthreads();
      body(qi, true, false);

      float l_p = (l4[0] + l4[1]) + (l4[2] + l4[3]);
      float l2 = l_p + __shfl_xor(l_p, 16);
      float lt = l2 + __shfl_xor(l2, 32);
      float inv = 1.f / lt;
      {
        int r = rw + l15;
        u16t* dst = AO + (size_t)(b * Nc + r) * Dc + h * HDc + q4 * 4;
        for (int dt = 0; dt < 4; dt++) {
          s16x4 o = pk4(accO[dt][0] * inv, accO[dt][1] * inv,
                        accO[dt][2] * inv, accO[dt][3] * inv);
          *(s16x4*)(dst + dt * 16) = o;
        }
      }
    }
  }
  gbar(ctr, 2304u);

  // ---------------- phase 3: output projection (r9 64x64, grid-stride) ---
  for (int pb = bid; pb < 1024; pb += 768) {
    u16t* pA = lE;                    // 4096 B
    u16t* pB = (u16t*)&Ps[0][0];      // 4096 B
    const int m0 = (pb & 63) * 64, n0 = (pb >> 6) * 64;
    const int wm = wave & 1, wn = wave >> 1;
    const int srow = t >> 2;
    const int scol = (t & 3) * 8;

    f32x4 acc[2][2];
    for (int i = 0; i < 2; i++)
      for (int j = 0; j < 2; j++)
        for (int r = 0; r < 4; r++) acc[i][j][r] = 0.f;

    for (int k0 = 0; k0 < Dc; k0 += 32) {
      __syncthreads();
      gld16(AO + (size_t)(m0 + srow) * Dc + k0 + scol, pA + wave * 512);
      gld16(wpb + (size_t)(n0 + srow) * Dc + k0 + scol, pB + wave * 512);
      __syncthreads();
      short8 af[2], bf[2];
      for (int i = 0; i < 2; i++) {
        af[i] = *(const short8*)(&pA[(wm * 32 + i * 16 + l15) * 32 + q4 * 8]);
        bf[i] = *(const short8*)(&pB[(wn * 32 + i * 16 + l15) * 32 + q4 * 8]);
      }
      for (int mi = 0; mi < 2; mi++)
        for (int ni = 0; ni < 2; ni++)
          acc[mi][ni] = MFMA16(af[mi], bf[ni], acc[mi][ni]);
    }

    for (int mi = 0; mi < 2; mi++)
      for (int ni = 0; ni < 2; ni++)
        for (int rg = 0; rg < 4; rg++) {
          int gm = m0 + wm * 32 + mi * 16 + q4 * 4 + rg;
          int gn = n0 + wn * 32 + ni * 16 + l15;
          out[(size_t)gm * Dc + gn] = acc[mi][ni][rg] + bp[gn];
        }
    __syncthreads();   // guard pA/pB reuse across grid-stride iterations
  }
}

// ---------------- host ----------------
extern "C" void kernel_launch(void* const* d_in, const int* in_sizes, int n_in,
                              void* d_out, int out_size, void* d_ws, size_t ws_size,
                              hipStream_t stream) {
  (void)in_sizes; (void)n_in; (void)out_size; (void)ws_size;
  const float* x   = (const float*)d_in[0];
  const float* Wq  = (const float*)d_in[1];
  const float* Wk  = (const float*)d_in[2];
  const float* Wv  = (const float*)d_in[3];
  const float* Wp  = (const float*)d_in[4];
  const float* bp  = (const float*)d_in[5];
  const float* rel = (const float*)d_in[6];
  float* out = (float*)d_out;

  char* ws = (char*)d_ws;
  u16t* xb  = (u16t*)(ws);
  u16t* wqb = (u16t*)(ws + 8388608);
  u16t* wkb = (u16t*)(ws + 10485760);
  u16t* wvb = (u16t*)(ws + 12582912);
  u16t* wpb = (u16t*)(ws + 14680064);
  u16t* Eb  = (u16t*)(ws + 16777216);   // 16*2128*64*2 = 4358144 B
  u16t* Qb  = (u16t*)(ws + 21233664);
  u16t* Kb  = (u16t*)(ws + 29622272);
  u16t* Vtb = (u16t*)(ws + 38010880);
  u16t* AOb = (u16t*)(ws + 46399488);   // ends at 54788096
  u32t* ctr = (u32t*)(ws + 54788096);   // [0]=barrier, [1]=attn ticket

  hipMemsetAsync(ctr, 0, 16, stream);   // graph-capturable (harness uses it)
  fused<<<dim3(768), dim3(256), 0, stream>>>(
      x, Wq, Wk, Wv, Wp, bp, rel, out,
      xb, wqb, wkb, wvb, wpb, Eb, Qb, Kb, Vtb, AOb, ctr);
}

// Round 13
// 581.548 us; speedup vs baseline: 1.9743x; 1.1919x over previous
//
#include <hip/hip_runtime.h>

typedef __attribute__((ext_vector_type(8))) short short8;
typedef __attribute__((ext_vector_type(4))) short s16x4;
typedef __attribute__((ext_vector_type(4))) float f32x4;
typedef unsigned short u16t;
typedef unsigned int u32t;

#define MFMA16(a,b,c) __builtin_amdgcn_mfma_f32_16x16x32_bf16((a),(b),(c),0,0,0)

__device__ __forceinline__ f32x4 mfma16x16(s16x4 a, s16x4 b, f32x4 c) {
#if __has_builtin(__builtin_amdgcn_mfma_f32_16x16x16bf16_1k)
  return __builtin_amdgcn_mfma_f32_16x16x16bf16_1k(a, b, c, 0, 0, 0);
#else
  __asm__("v_mfma_f32_16x16x16_bf16 %0, %1, %2, %0" : "+v"(c) : "v"(a), "v"(b));
  return c;
#endif
}

constexpr int Bc = 2, Nc = 2048, Dc = 1024, NHc = 16, HDc = 64;
constexpr int EStride = Nc + 80;   // E rows per head incl. zero pad

__device__ __forceinline__ u16t f2bf(float f) {   // RTN (cold paths)
  union { float f; u32t u; } v; v.f = f;
  u32t r = v.u + 0x7FFFu + ((v.u >> 16) & 1u);
  return (u16t)(r >> 16);
}
#if __has_builtin(__builtin_amdgcn_cvt_pk_bf16_f32)
__device__ __forceinline__ u32t pk2(float a, float b) {
  auto r = __builtin_amdgcn_cvt_pk_bf16_f32(a, b);
  return __builtin_bit_cast(u32t, r);
}
#else
__device__ __forceinline__ u32t pk2(float a, float b) {
  u32t ua = __builtin_bit_cast(u32t, a);
  u32t ub = __builtin_bit_cast(u32t, b);
  return ((ua + 0x8000u) >> 16) | ((ub + 0x8000u) & 0xFFFF0000u);
}
#endif
__device__ __forceinline__ s16x4 pk4(float a, float b, float c, float d) {
  union { u32t u[2]; s16x4 s; } r;
  r.u[0] = pk2(a, b); r.u[1] = pk2(c, d);
  return r.s;
}

__device__ __forceinline__ s16x4 lo4(short8 v) {
  return __builtin_shufflevector(v, v, 0, 1, 2, 3);
}
__device__ __forceinline__ s16x4 hi4(short8 v) {
  return __builtin_shufflevector(v, v, 4, 5, 6, 7);
}

// async global->LDS, 16B per lane
__device__ __forceinline__ void gld16(const u16t* g, u16t* l) {
  __builtin_amdgcn_global_load_lds(
      (const __attribute__((address_space(1))) unsigned int*)(g),
      (__attribute__((address_space(3))) unsigned int*)(l), 16, 0, 0);
}

__device__ __forceinline__ void cvt4(const float* s, u16t* d) {
  f32x4 v = *(const f32x4*)s;
  u32t* dp = (u32t*)d;
  dp[0] = pk2(v[0], v[1]); dp[1] = pk2(v[2], v[3]);
}

// Persistent-grid device barrier (r12 version — proven correct & cheap).
// RELAXED spin loads polled every ~1.7us; ordering via one fence before the
// add (release) + one after the spin (acquire). Deadlock-proof: grid 768 ==
// guaranteed resident capacity (launch_bounds(256,3): 3 blocks/CU x 256CU);
// bounded spin -> wrong answer, never a hung container.
__device__ __forceinline__ void gbar(u32t* bar, u32t target) {
  __syncthreads();
  if (threadIdx.x == 0) {
    __threadfence();   // release: this phase's writes visible device-wide
    __hip_atomic_fetch_add(bar, 1u, __ATOMIC_RELAXED, __HIP_MEMORY_SCOPE_AGENT);
    u32t spins = 0;
    while (__hip_atomic_load(bar, __ATOMIC_RELAXED, __HIP_MEMORY_SCOPE_AGENT) <
               target && ++spins < 2000000u)
      __builtin_amdgcn_s_sleep(64);
    __threadfence();   // acquire: drop stale lines before reading peers' data
  }
  __syncthreads();
}

// ======================= FUSED persistent kernel =======================
// ROUND-13 FIX: launch_bounds (256,4) -> (256,3). r11/r12's VGPR_Count=64
// (vs 80/84 for the SAME phase bodies standalone) proves the 128-VGPR cap
// forced scratch spills of the attn phase's register arrays; scratch is
// global memory -> the 367MB FETCH / 476MB WRITE (identical r11<->r12, so
// NOT the barrier) and the traffic-bound 693us. (256,3) caps at ~170 VGPR
// (no spill) and still guarantees 3 blocks/CU x 256 = 768 resident = grid
// (LDS 40448B allows 4/CU). Everything else byte-identical to r12 (passed).
__global__ __launch_bounds__(256, 3) void fused(
    const float* __restrict__ x, const float* __restrict__ wq,
    const float* __restrict__ wk, const float* __restrict__ wv,
    const float* __restrict__ wp, const float* __restrict__ bp,
    const float* __restrict__ rel, float* __restrict__ out,
    u16t* __restrict__ xb, u16t* __restrict__ wqb, u16t* __restrict__ wkb,
    u16t* __restrict__ wvb, u16t* __restrict__ wpb, u16t* __restrict__ Eb,
    u16t* __restrict__ Qb, u16t* __restrict__ Kb, u16t* __restrict__ Vt,
    u16t* __restrict__ AO, u32t* __restrict__ ctr) {
  __shared__ __align__(16) u16t lE[128 * 72];      // 18432 B (aliased)
  __shared__ __align__(16) float Ps[4][16 * 84];   // 21504 B (aliased)
  __shared__ u32t sTau;

  const int bid = blockIdx.x;
  const int t = threadIdx.x, wave = t >> 6, lane = t & 63;
  const int l15 = lane & 15, q4 = lane >> 4;

  // ---------------- phase 0: conversions (grid-stride, 768 blocks) ------
  for (int i = bid * 256 + t; i < 2641920; i += 196608) {
    if (i < 1048576) {                        // x
      cvt4(x + (size_t)i * 4, xb + (size_t)i * 4);
    } else if (i < 2097152) {                 // weights
      int r = i - 1048576;
      int w = r >> 18;
      int k = (r & 262143) * 4;
      const float* s = (w == 0) ? wq : (w == 1) ? wk : (w == 2) ? wv : wp;
      u16t* d = (w == 0) ? wqb : (w == 1) ? wkb : (w == 2) ? wvb : wpb;
      cvt4(s + k, d + k);
    } else if (i < 2621440) {                 // E remap to [h][m][hd]
      int r = i - 2097152;
      int flat = r * 4;
      int h = flat >> 17;
      int rem = flat & 131071;
      int m = rem >> 6, d = rem & 63;
      cvt4(rel + (size_t)m * Dc + h * HDc + d,
           Eb + ((size_t)h * EStride + m) * HDc + d);
    } else {                                  // zero pad rows [Nc, Nc+80)
      int r = i - 2621440;
      int flat = r * 4;
      int h = flat / 5120;
      int rem = flat - h * 5120;
      int pr = rem >> 6, d = rem & 63;
      u32t* dp = (u32t*)(Eb + ((size_t)h * EStride + Nc + pr) * HDc + d);
      dp[0] = 0; dp[1] = 0;
    }
  }
  gbar(ctr, 768u);

  // ---------------- phase 1: QKV GEMM (768 blocks, r6 structure 1:1) ----
  {
    u16t* lA = lE;                    // 8192 B
    u16t* lB = (u16t*)&Ps[0][0];      // 8192 B
    const int bx = bid & 31, y = bid >> 5, which = y >> 3;
    const u16t* W = (which == 0) ? wqb : (which == 1) ? wkb : wvb;
    const float sc = 0.18033688011112042f;    // Q only
    const int m0 = bx * 128, n0 = (y & 7) * 128;
    const int wm = wave & 1, wn = wave >> 1;
    const int srow = wave * 16 + (lane >> 2);
    const int scol = (lane & 3) * 8;

    f32x4 acc[4][4];
    for (int i = 0; i < 4; i++)
      for (int j = 0; j < 4; j++)
        for (int r = 0; r < 4; r++) acc[i][j][r] = 0.f;

    for (int k0 = 0; k0 < Dc; k0 += 32) {
      __syncthreads();
      for (int r = 0; r < 2; r++) {
        int row = srow + r * 64;
        gld16(xb + (size_t)(m0 + row) * Dc + k0 + scol, lA + wave * 512 + r * 2048);
        gld16(W + (size_t)(n0 + row) * Dc + k0 + scol, lB + wave * 512 + r * 2048);
      }
      __syncthreads();
      short8 af[4], bf[4];
      for (int i = 0; i < 4; i++) {
        af[i] = *(const short8*)(&lA[(wm * 64 + i * 16 + l15) * 32 + q4 * 8]);
        bf[i] = *(const short8*)(&lB[(wn * 64 + i * 16 + l15) * 32 + q4 * 8]);
      }
      for (int mi = 0; mi < 4; mi++)
        for (int ni = 0; ni < 4; ni++)
          acc[mi][ni] = MFMA16(af[mi], bf[ni], acc[mi][ni]);
    }

    if (which == 0) {
      for (int mi = 0; mi < 4; mi++)
        for (int ni = 0; ni < 4; ni++)
          for (int rg = 0; rg < 4; rg++) {
            int gm = m0 + wm * 64 + mi * 16 + q4 * 4 + rg;
            int gn = n0 + wn * 64 + ni * 16 + l15;
            int b = gm >> 11, n = gm & 2047, h = gn >> 6, hd = gn & 63;
            Qb[(((size_t)(b * NHc + h) * Nc + n) * HDc) + hd] =
                f2bf(acc[mi][ni][rg] * sc);
          }
    } else if (which == 1) {
      for (int mi = 0; mi < 4; mi++)
        for (int ni = 0; ni < 4; ni++)
          for (int rg = 0; rg < 4; rg++) {
            int gm = m0 + wm * 64 + mi * 16 + q4 * 4 + rg;
            int gn = n0 + wn * 64 + ni * 16 + l15;
            int b = gm >> 11, n = gm & 2047, h = gn >> 6, hd = gn & 63;
            size_t off = (size_t)(b * NHc + h) * Nc * HDc
                       + (size_t)(n >> 6) * 4096
                       + ((((n >> 4) & 3) * 2 + (hd >> 5)) * 512)
                       + (((hd >> 3) & 3) * 128) + ((n & 15) * 8) + (hd & 7);
            Kb[off] = f2bf(acc[mi][ni][rg]);
          }
    } else {
      for (int mi = 0; mi < 4; mi++)
        for (int ni = 0; ni < 4; ni++) {
          int gm = m0 + wm * 64 + mi * 16 + q4 * 4;       // n base (rg=0)
          int gn = n0 + wn * 64 + ni * 16 + l15;
          int b = gm >> 11, n = gm & 2047, h = gn >> 6, hd = gn & 63;
          s16x4 pkv = pk4(acc[mi][ni][0], acc[mi][ni][1],
                          acc[mi][ni][2], acc[mi][ni][3]);
          size_t off = (size_t)(b * NHc + h) * Nc * HDc
                     + (size_t)(n >> 6) * 4096
                     + (((hd >> 4) * 2 + ((n >> 5) & 1)) * 512)
                     + (((n >> 2) & 3) * 128) + ((hd & 15) * 8)
                     + (((n >> 4) & 1) * 4);
          *(s16x4*)(&Vt[off]) = pkv;
        }
    }
  }
  gbar(ctr, 1536u);

  // ---------------- phase 2: attn (r2 dbuf body, atomic work ticket) ----
  // Ticket order tau -> qi = 31-(tau>>5): longest-first + true backfill.
  {
    const int tbase = (3 - wave) * 16;
    const int Tm = wave * 16 + l15;
    float* Pw = Ps[wave];
    const int sr = t >> 3, sc8 = (t & 7) * 8;
    const int sr2 = sr + 32;

    for (;;) {
      if (t == 0) sTau = atomicAdd(&ctr[1], 1u);
      __syncthreads();               // broadcast + guards lE/Ps vs prev tile
      u32t tau = sTau;
      if (tau >= 1024u) break;
      const int qi = 31 - ((int)tau >> 5);
      const int bh = (int)tau & 31;
      const int b = bh >> 4, h = bh & 15;
      const u16t* Qh = Qb + (size_t)(b * NHc + h) * Nc * HDc;
      const u16t* Kh = Kb + (size_t)(b * NHc + h) * Nc * HDc;  // frag layout
      const u16t* Vh = Vt + (size_t)(b * NHc + h) * Nc * HDc;  // frag layout
      const u16t* Eh = Eb + (size_t)h * EStride * HDc;
      const int r0 = qi * 64;
      const int rw = r0 + wave * 16;
      const int ebase0 = Nc - 63 - r0;

      short8 qf[2], qsf[2];
      {
        int r = rw + l15;
        int rs = r - 1; if (rs < 0) rs = 0;
        for (int kh = 0; kh < 2; kh++) {
          qf[kh]  = *(const short8*)(Qh + (size_t)r * HDc + kh * 32 + q4 * 8);
          qsf[kh] = *(const short8*)(Qh + (size_t)rs * HDc + kh * 32 + q4 * 8);
        }
      }

      f32x4 accO[4];
      f32x4 l4;
      for (int rg = 0; rg < 4; rg++) l4[rg] = 0.f;
      for (int dt = 0; dt < 4; dt++)
        for (int rg = 0; rg < 4; rg++) accO[dt][rg] = 0.f;

      short8 kf[8];
#pragma unroll
      for (int i = 0; i < 8; i++)
        kf[i] = *(const short8*)(Kh + i * 512 + lane * 8);

      auto body = [&](int j, bool last, bool pf) {
        const u16t* Vj = Vh + (size_t)j * 4096;
        short8 vf[8];
#pragma unroll
        for (int i = 0; i < 8; i++)
          vf[i] = *(const short8*)(Vj + i * 512 + lane * 8);

        f32x4 accS[4];
        for (int ct = 0; ct < 4; ct++)
          for (int rg = 0; rg < 4; rg++) accS[ct][rg] = 0.f;
#pragma unroll
        for (int kh = 0; kh < 2; kh++)
#pragma unroll
          for (int ct = 0; ct < 4; ct++)
            accS[ct] = MFMA16(kf[ct * 2 + kh], qf[kh], accS[ct]);

        if (pf) {
          const u16t* Kn = Kh + (size_t)(j + 1) * 4096;
#pragma unroll
          for (int i = 0; i < 8; i++)
            kf[i] = *(const short8*)(Kn + i * 512 + lane * 8);
        }

        const int rot = (j & 1) << 6;
        const int pb = tbase + l15 + rot;
#pragma unroll
        for (int pt = 0; pt < 5; pt++) {
          int pr = (pb + pt * 16) & 127;
          f32x4 ap;
          ap[0] = 0.f; ap[1] = 0.f; ap[2] = 0.f; ap[3] = 0.f;
#pragma unroll
          for (int kh = 0; kh < 2; kh++) {
            short8 efr = *(const short8*)(&lE[pr * 72 + kh * 32 + q4 * 8]);
            ap = MFMA16(efr, qsf[kh], ap);
          }
          *(f32x4*)(&Pw[l15 * 84 + pt * 16 + q4 * 4]) = ap;
        }

        __asm__ volatile("s_waitcnt lgkmcnt(0)" ::: "memory");
        __builtin_amdgcn_sched_barrier(0);
        const int rbase = l15 * 83 + q4 * 4 + 15;
        s16x4 bq[4];
#pragma unroll
        for (int ct = 0; ct < 4; ct++) {
          float pv[4];
#pragma unroll
          for (int rg = 0; rg < 4; rg++) {
            float s = accS[ct][rg] + Pw[rbase + ct * 16 + rg];
            if (last && (ct * 16 + q4 * 4 + rg) > Tm) s = -1e30f;
            float p = exp2f(s);
            l4[rg] += p;
            pv[rg] = p;
          }
          bq[ct] = pk4(pv[0], pv[1], pv[2], pv[3]);
        }
        __asm__ volatile("" ::: "memory");
#pragma unroll
        for (int dt = 0; dt < 4; dt++)
#pragma unroll
          for (int ks = 0; ks < 4; ks++) {
            s16x4 vfr = (ks & 1) ? hi4(vf[dt * 2 + (ks >> 1)])
                                 : lo4(vf[dt * 2 + (ks >> 1)]);
            accO[dt] = mfma16x16(vfr, bq[ks], accO[dt]);
          }
      };

      // init lE phys [0,128) = E rows ebase0+[0,128)
      for (int i = 0; i < 4; i++) {
        int cc = t + i * 256;
        int s = cc >> 3, c8 = (cc & 7) * 8;
        *(f32x4*)(&lE[s * 72 + c8]) =
            *(const f32x4*)(Eh + (size_t)(ebase0 + s) * HDc + c8);
      }

      for (int j = 0; j < qi; j++) {
        __syncthreads();
        const int ebn = ebase0 + 64 * j + 128;     // chunk for step j+1
        f32x4 pE0 = *(const f32x4*)(Eh + (size_t)(ebn + sr) * HDc + sc8);
        f32x4 pE1 = *(const f32x4*)(Eh + (size_t)(ebn + sr2) * HDc + sc8);
        body(j, false, true);
        __syncthreads();
        int ph0 = (sr + 64 * j) & 127;
        int ph1 = (sr2 + 64 * j) & 127;
        *(f32x4*)(&lE[ph0 * 72 + sc8]) = pE0;
        *(f32x4*)(&lE[ph1 * 72 + sc8]) = pE1;
      }
      __syncthreads();
      body(qi, true, false);

      float l_p = (l4[0] + l4[1]) + (l4[2] + l4[3]);
      float l2 = l_p + __shfl_xor(l_p, 16);
      float lt = l2 + __shfl_xor(l2, 32);
      float inv = 1.f / lt;
      {
        int r = rw + l15;
        u16t* dst = AO + (size_t)(b * Nc + r) * Dc + h * HDc + q4 * 4;
        for (int dt = 0; dt < 4; dt++) {
          s16x4 o = pk4(accO[dt][0] * inv, accO[dt][1] * inv,
                        accO[dt][2] * inv, accO[dt][3] * inv);
          *(s16x4*)(dst + dt * 16) = o;
        }
      }
    }
  }
  gbar(ctr, 2304u);

  // ---------------- phase 3: output projection (r9 64x64, grid-stride) ---
  for (int pb = bid; pb < 1024; pb += 768) {
    u16t* pA = lE;                    // 4096 B
    u16t* pB = (u16t*)&Ps[0][0];      // 4096 B
    const int m0 = (pb & 63) * 64, n0 = (pb >> 6) * 64;
    const int wm = wave & 1, wn = wave >> 1;
    const int srow = t >> 2;
    const int scol = (t & 3) * 8;

    f32x4 acc[2][2];
    for (int i = 0; i < 2; i++)
      for (int j = 0; j < 2; j++)
        for (int r = 0; r < 4; r++) acc[i][j][r] = 0.f;

    for (int k0 = 0; k0 < Dc; k0 += 32) {
      __syncthreads();
      gld16(AO + (size_t)(m0 + srow) * Dc + k0 + scol, pA + wave * 512);
      gld16(wpb + (size_t)(n0 + srow) * Dc + k0 + scol, pB + wave * 512);
      __syncthreads();
      short8 af[2], bf[2];
      for (int i = 0; i < 2; i++) {
        af[i] = *(const short8*)(&pA[(wm * 32 + i * 16 + l15) * 32 + q4 * 8]);
        bf[i] = *(const short8*)(&pB[(wn * 32 + i * 16 + l15) * 32 + q4 * 8]);
      }
      for (int mi = 0; mi < 2; mi++)
        for (int ni = 0; ni < 2; ni++)
          acc[mi][ni] = MFMA16(af[mi], bf[ni], acc[mi][ni]);
    }

    for (int mi = 0; mi < 2; mi++)
      for (int ni = 0; ni < 2; ni++)
        for (int rg = 0; rg < 4; rg++) {
          int gm = m0 + wm * 32 + mi * 16 + q4 * 4 + rg;
          int gn = n0 + wn * 32 + ni * 16 + l15;
          out[(size_t)gm * Dc + gn] = acc[mi][ni][rg] + bp[gn];
        }
    __syncthreads();   // guard pA/pB reuse across grid-stride iterations
  }
}

// ---------------- host ----------------
extern "C" void kernel_launch(void* const* d_in, const int* in_sizes, int n_in,
                              void* d_out, int out_size, void* d_ws, size_t ws_size,
                              hipStream_t stream) {
  (void)in_sizes; (void)n_in; (void)out_size; (void)ws_size;
  const float* x   = (const float*)d_in[0];
  const float* Wq  = (const float*)d_in[1];
  const float* Wk  = (const float*)d_in[2];
  const float* Wv  = (const float*)d_in[3];
  const float* Wp  = (const float*)d_in[4];
  const float* bp  = (const float*)d_in[5];
  const float* rel = (const float*)d_in[6];
  float* out = (float*)d_out;

  char* ws = (char*)d_ws;
  u16t* xb  = (u16t*)(ws);
  u16t* wqb = (u16t*)(ws + 8388608);
  u16t* wkb = (u16t*)(ws + 10485760);
  u16t* wvb = (u16t*)(ws + 12582912);
  u16t* wpb = (u16t*)(ws + 14680064);
  u16t* Eb  = (u16t*)(ws + 16777216);   // 16*2128*64*2 = 4358144 B
  u16t* Qb  = (u16t*)(ws + 21233664);
  u16t* Kb  = (u16t*)(ws + 29622272);
  u16t* Vtb = (u16t*)(ws + 38010880);
  u16t* AOb = (u16t*)(ws + 46399488);   // ends at 54788096
  u32t* ctr = (u32t*)(ws + 54788096);   // [0]=barrier, [1]=attn ticket

  hipMemsetAsync(ctr, 0, 16, stream);   // graph-capturable (harness uses it)
  fused<<<dim3(768), dim3(256), 0, stream>>>(
      x, Wq, Wk, Wv, Wp, bp, rel, out,
      xb, wqb, wkb, wvb, wpb, Eb, Qb, Kb, Vtb, AOb, ctr);
}

// Round 15
// 199.347 us; speedup vs baseline: 5.7596x; 2.9173x over previous
//
#include <hip/hip_runtime.h>

typedef __attribute__((ext_vector_type(8))) short short8;
typedef __attribute__((ext_vector_type(4))) short s16x4;
typedef __attribute__((ext_vector_type(4))) float f32x4;
typedef unsigned short u16t;
typedef unsigned int u32t;

#define MFMA16(a,b,c) __builtin_amdgcn_mfma_f32_16x16x32_bf16((a),(b),(c),0,0,0)

__device__ __forceinline__ f32x4 mfma16x16(s16x4 a, s16x4 b, f32x4 c) {
#if __has_builtin(__builtin_amdgcn_mfma_f32_16x16x16bf16_1k)
  return __builtin_amdgcn_mfma_f32_16x16x16bf16_1k(a, b, c, 0, 0, 0);
#else
  __asm__("v_mfma_f32_16x16x16_bf16 %0, %1, %2, %0" : "+v"(c) : "v"(a), "v"(b));
  return c;
#endif
}

constexpr int Bc = 2, Nc = 2048, Dc = 1024, NHc = 16, HDc = 64;
constexpr int EStride = Nc + 80;   // E rows per head incl. zero pad

__device__ __forceinline__ u16t f2bf(float f) {   // RTN (cold paths)
  union { float f; u32t u; } v; v.f = f;
  u32t r = v.u + 0x7FFFu + ((v.u >> 16) & 1u);
  return (u16t)(r >> 16);
}
// pack two floats -> bf16x2; HW packed cvt when available
#if __has_builtin(__builtin_amdgcn_cvt_pk_bf16_f32)
__device__ __forceinline__ u32t pk2(float a, float b) {
  auto r = __builtin_amdgcn_cvt_pk_bf16_f32(a, b);
  return __builtin_bit_cast(u32t, r);
}
#else
__device__ __forceinline__ u32t pk2(float a, float b) {
  u32t ua = __builtin_bit_cast(u32t, a);
  u32t ub = __builtin_bit_cast(u32t, b);
  return ((ua + 0x8000u) >> 16) | ((ub + 0x8000u) & 0xFFFF0000u);
}
#endif
__device__ __forceinline__ s16x4 pk4(float a, float b, float c, float d) {
  union { u32t u[2]; s16x4 s; } r;
  r.u[0] = pk2(a, b); r.u[1] = pk2(c, d);
  return r.s;
}

__device__ __forceinline__ s16x4 lo4(short8 v) {
  return __builtin_shufflevector(v, v, 0, 1, 2, 3);
}
__device__ __forceinline__ s16x4 hi4(short8 v) {
  return __builtin_shufflevector(v, v, 4, 5, 6, 7);
}

// async global->LDS, 16B per lane
__device__ __forceinline__ void gld16(const u16t* g, u16t* l) {
  __builtin_amdgcn_global_load_lds(
      (const __attribute__((address_space(1))) unsigned int*)(g),
      (__attribute__((address_space(3))) unsigned int*)(l), 16, 0, 0);
}

// ---------------- fused conversion: x, 4 weights, E remap + zero pad ----------------
__device__ __forceinline__ void cvt4(const float* s, u16t* d) {
  f32x4 v = *(const f32x4*)s;
  u32t* dp = (u32t*)d;
  dp[0] = pk2(v[0], v[1]); dp[1] = pk2(v[2], v[3]);
}

__global__ __launch_bounds__(256) void cvt_all(
    const float* __restrict__ x, const float* __restrict__ wq,
    const float* __restrict__ wk, const float* __restrict__ wv,
    const float* __restrict__ wp, const float* __restrict__ rel,
    u16t* __restrict__ xb, u16t* __restrict__ wqb, u16t* __restrict__ wkb,
    u16t* __restrict__ wvb, u16t* __restrict__ wpb, u16t* __restrict__ Eb) {
  int i = blockIdx.x * 256 + threadIdx.x;
  if (i < 1048576) {                        // x
    cvt4(x + (size_t)i * 4, xb + (size_t)i * 4);
  } else if (i < 2097152) {                 // weights
    int r = i - 1048576;
    int w = r >> 18;
    int k = (r & 262143) * 4;
    const float* s = (w == 0) ? wq : (w == 1) ? wk : (w == 2) ? wv : wp;
    u16t* d = (w == 0) ? wqb : (w == 1) ? wkb : (w == 2) ? wvb : wpb;
    cvt4(s + k, d + k);
  } else if (i < 2621440) {                 // E remap to [h][m][hd]
    int r = i - 2097152;
    int flat = r * 4;
    int h = flat >> 17;
    int rem = flat & 131071;
    int m = rem >> 6, d = rem & 63;
    cvt4(rel + (size_t)m * Dc + h * HDc + d,
         Eb + ((size_t)h * EStride + m) * HDc + d);
  } else {                                  // zero pad rows [Nc, Nc+80)
    int r = i - 2621440;
    int flat = r * 4;
    int h = flat / 5120;
    int rem = flat - h * 5120;
    int pr = rem >> 6, d = rem & 63;
    u32t* dp = (u32t*)(Eb + ((size_t)h * EStride + Nc + pr) * HDc + d);
    dp[0] = 0; dp[1] = 0;
  }
}

// ---------------- fused QKV GEMM: out = x @ W^T ----------------
// ROUND-6 VERSION (38.5us isolated via r6<->r8 totals). Q row-major
// pre-scaled by 0.125*log2(e); K and V in attn MFMA FRAG layout.
// Session note: the r7/r8 rework (operand swap + which-branch in the K-loop)
// doubled this kernel; the r8 coalesced-store fix left WRITE_SIZE unchanged,
// falsifying write-amplification as the cause. Do not re-derive without
// isolating the mechanism first.
__global__ __launch_bounds__(256, 3) void gemm_qkv(const u16t* __restrict__ A,
    const u16t* __restrict__ Wq, const u16t* __restrict__ Wk,
    const u16t* __restrict__ Wv, u16t* __restrict__ Qb,
    u16t* __restrict__ Kb, u16t* __restrict__ Vt) {
  __shared__ u16t lA[128 * 32];   // unpadded: required by global_load_lds
  __shared__ u16t lB[128 * 32];
  const int y = blockIdx.y, which = y >> 3;
  const u16t* W = (which == 0) ? Wq : (which == 1) ? Wk : Wv;
  const float sc = 0.18033688011112042f;    // Q only
  const int m0 = blockIdx.x * 128, n0 = (y & 7) * 128;
  const int t = threadIdx.x, wave = t >> 6, lane = t & 63;
  const int l15 = lane & 15, q4 = lane >> 4, wm = wave & 1, wn = wave >> 1;
  const int srow = wave * 16 + (lane >> 2);
  const int scol = (lane & 3) * 8;

  f32x4 acc[4][4];
  for (int i = 0; i < 4; i++)
    for (int j = 0; j < 4; j++)
      for (int r = 0; r < 4; r++) acc[i][j][r] = 0.f;

  for (int k0 = 0; k0 < Dc; k0 += 32) {
    __syncthreads();
    for (int r = 0; r < 2; r++) {
      int row = srow + r * 64;
      gld16(A + (size_t)(m0 + row) * Dc + k0 + scol, lA + wave * 512 + r * 2048);
      gld16(W + (size_t)(n0 + row) * Dc + k0 + scol, lB + wave * 512 + r * 2048);
    }
    __syncthreads();
    short8 af[4], bf[4];
    for (int i = 0; i < 4; i++) {
      af[i] = *(const short8*)(&lA[(wm * 64 + i * 16 + l15) * 32 + q4 * 8]);
      bf[i] = *(const short8*)(&lB[(wn * 64 + i * 16 + l15) * 32 + q4 * 8]);
    }
    for (int mi = 0; mi < 4; mi++)
      for (int ni = 0; ni < 4; ni++)
        acc[mi][ni] = MFMA16(af[mi], bf[ni], acc[mi][ni]);
  }

  if (which == 0) {
    for (int mi = 0; mi < 4; mi++)
      for (int ni = 0; ni < 4; ni++)
        for (int rg = 0; rg < 4; rg++) {
          int gm = m0 + wm * 64 + mi * 16 + q4 * 4 + rg;
          int gn = n0 + wn * 64 + ni * 16 + l15;
          int b = gm >> 11, n = gm & 2047, h = gn >> 6, hd = gn & 63;
          Qb[(((size_t)(b * NHc + h) * Nc + n) * HDc) + hd] =
              f2bf(acc[mi][ni][rg] * sc);
        }
  } else if (which == 1) {
    for (int mi = 0; mi < 4; mi++)
      for (int ni = 0; ni < 4; ni++)
        for (int rg = 0; rg < 4; rg++) {
          int gm = m0 + wm * 64 + mi * 16 + q4 * 4 + rg;
          int gn = n0 + wn * 64 + ni * 16 + l15;
          int b = gm >> 11, n = gm & 2047, h = gn >> 6, hd = gn & 63;
          size_t off = (size_t)(b * NHc + h) * Nc * HDc
                     + (size_t)(n >> 6) * 4096
                     + ((((n >> 4) & 3) * 2 + (hd >> 5)) * 512)
                     + (((hd >> 3) & 3) * 128) + ((n & 15) * 8) + (hd & 7);
          Kb[off] = f2bf(acc[mi][ni][rg]);
        }
  } else {
    // V: rows of acc (rg) are consecutive n -> contiguous 8B in frag layout.
    for (int mi = 0; mi < 4; mi++)
      for (int ni = 0; ni < 4; ni++) {
        int gm = m0 + wm * 64 + mi * 16 + q4 * 4;       // n base (rg=0)
        int gn = n0 + wn * 64 + ni * 16 + l15;
        int b = gm >> 11, n = gm & 2047, h = gn >> 6, hd = gn & 63;
        s16x4 pkv = pk4(acc[mi][ni][0], acc[mi][ni][1],
                        acc[mi][ni][2], acc[mi][ni][3]);
        size_t off = (size_t)(b * NHc + h) * Nc * HDc
                   + (size_t)(n >> 6) * 4096
                   + (((hd >> 4) * 2 + ((n >> 5) & 1)) * 512)
                   + (((n >> 2) & 3) * 128) + ((hd & 15) * 8)
                   + (((n >> 4) & 1) * 4);
        *(s16x4*)(&Vt[off]) = pkv;
      }
  }
}

// ---------------- output projection GEMM: out = AO @ Wp^T + bp (fp32) ----------------
// ROUND-9 VERSION: 64x64 tiles, dim3(64,16) = 1024 blocks = 4/CU.
__global__ __launch_bounds__(256, 4) void gemm_proj(const u16t* __restrict__ A,
    const u16t* __restrict__ W, float* __restrict__ outf,
    const float* __restrict__ bias) {
  __shared__ u16t lA[64 * 32];
  __shared__ u16t lB[64 * 32];
  const int m0 = blockIdx.x * 64, n0 = blockIdx.y * 64;
  const int t = threadIdx.x, wave = t >> 6, lane = t & 63;
  const int l15 = lane & 15, q4 = lane >> 4, wm = wave & 1, wn = wave >> 1;
  const int srow = t >> 2;            // 256 threads cover 64 rows x 32 cols
  const int scol = (t & 3) * 8;

  f32x4 acc[2][2];
  for (int i = 0; i < 2; i++)
    for (int j = 0; j < 2; j++)
      for (int r = 0; r < 4; r++) acc[i][j][r] = 0.f;

  for (int k0 = 0; k0 < Dc; k0 += 32) {
    __syncthreads();
    gld16(A + (size_t)(m0 + srow) * Dc + k0 + scol, lA + wave * 512);
    gld16(W + (size_t)(n0 + srow) * Dc + k0 + scol, lB + wave * 512);
    __syncthreads();
    short8 af[2], bf[2];
    for (int i = 0; i < 2; i++) {
      af[i] = *(const short8*)(&lA[(wm * 32 + i * 16 + l15) * 32 + q4 * 8]);
      bf[i] = *(const short8*)(&lB[(wn * 32 + i * 16 + l15) * 32 + q4 * 8]);
    }
    for (int mi = 0; mi < 2; mi++)
      for (int ni = 0; ni < 2; ni++)
        acc[mi][ni] = MFMA16(af[mi], bf[ni], acc[mi][ni]);
  }

  for (int mi = 0; mi < 2; mi++)
    for (int ni = 0; ni < 2; ni++)
      for (int rg = 0; rg < 4; rg++) {
        int gm = m0 + wm * 32 + mi * 16 + q4 * 4 + rg;
        int gn = n0 + wn * 32 + ni * 16 + l15;
        outf[(size_t)gm * Dc + gn] = acc[mi][ni][rg] + bias[gn];
      }
}

// ---------------- fused causal attention (transposed compute) ----------------
// Round-6/9 version (best measured: 63.6us). Tri-buffered lE (one barrier
// per step), frag-layout K/V direct from global (L1 broadcast), K prefetch
// one step ahead, longest-first tiles + hardware backfill (grid 1024 >
// ~3/CU resident capacity).
__global__ __launch_bounds__(256, 3) void attn(const u16t* __restrict__ Qb,
                                               const u16t* __restrict__ Kb,
                                               const u16t* __restrict__ Vt,
                                               const u16t* __restrict__ Eb,
                                               u16t* __restrict__ AO) {
  __shared__ u16t lE[192 * 72];      // 27648 B tri-buffer
  __shared__ float Ps[4][16 * 84];   // 21504 B wave-private fp32 srel scratch

  const int bid = blockIdx.x;
  const int qi = 31 - (bid >> 5);    // longest tiles dispatched first
  const int bh = bid & 31;
  const int b = bh >> 4, h = bh & 15;

  const u16t* Qh = Qb + (size_t)(b * NHc + h) * Nc * HDc;
  const u16t* Kh = Kb + (size_t)(b * NHc + h) * Nc * HDc;  // frag layout
  const u16t* Vh = Vt + (size_t)(b * NHc + h) * Nc * HDc;  // frag layout
  const u16t* Eh = Eb + (size_t)h * EStride * HDc;

  const int t = threadIdx.x, wave = t >> 6, lane = t & 63, l15 = lane & 15, q4 = lane >> 4;
  const int tbase = (3 - wave) * 16;
  const int Tm = wave * 16 + l15;    // causal threshold for the final step
  float* Pw = Ps[wave];

  const int sr = t >> 3, sc8 = (t & 7) * 8;
  const int sr2 = sr + 32;

  const int r0 = qi * 64;
  const int rw = r0 + wave * 16;
  const int ebase0 = Nc - 63 - r0;

  short8 qf[2], qsf[2];
  {
    int r = rw + l15;
    int rs = r - 1; if (rs < 0) rs = 0;
    for (int kh = 0; kh < 2; kh++) {
      qf[kh]  = *(const short8*)(Qh + (size_t)r * HDc + kh * 32 + q4 * 8);
      qsf[kh] = *(const short8*)(Qh + (size_t)rs * HDc + kh * 32 + q4 * 8);
    }
  }

  f32x4 accO[4];
  f32x4 l4;                          // 4-way partial row-sums
  for (int rg = 0; rg < 4; rg++) l4[rg] = 0.f;
  for (int dt = 0; dt < 4; dt++)
    for (int rg = 0; rg < 4; rg++) accO[dt][rg] = 0.f;

  // K fragments for the CURRENT step (prefetched one step ahead)
  short8 kf[8];
#pragma unroll
  for (int i = 0; i < 8; i++)
    kf[i] = *(const short8*)(Kh + i * 512 + lane * 8);

  // step body. basej = (64*j)%192. pf: prefetch K for step j+1.
  auto body = [&](int j, int basej, bool last, bool pf) {
    const u16t* Vj = Vh + (size_t)j * 4096;
    short8 vf[8];
#pragma unroll
    for (int i = 0; i < 8; i++)
      vf[i] = *(const short8*)(Vj + i * 512 + lane * 8);

    // ---- S^T = MFMA(K, Q): operands already resident (prefetched) ----
    f32x4 accS[4];
    for (int ct = 0; ct < 4; ct++)
      for (int rg = 0; rg < 4; rg++) accS[ct][rg] = 0.f;
#pragma unroll
    for (int kh = 0; kh < 2; kh++)
#pragma unroll
      for (int ct = 0; ct < 4; ct++)
        accS[ct] = MFMA16(kf[ct * 2 + kh], qf[kh], accS[ct]);

    // ---- prefetch K for next step (kf's only consumer was S above) ----
    if (pf) {
      const u16t* Kn = Kh + (size_t)(j + 1) * 4096;
#pragma unroll
      for (int i = 0; i < 8; i++)
        kf[i] = *(const short8*)(Kn + i * 512 + lane * 8);
    }

    // ---- Pe^T = MFMA(E, Qs) from LDS tri-buffer; write Ps per tile ----
    const int pb = basej + tbase + l15;
#pragma unroll
    for (int pt = 0; pt < 5; pt++) {
      int pr = pb + pt * 16; if (pr >= 192) pr -= 192;
      f32x4 ap;
      ap[0] = 0.f; ap[1] = 0.f; ap[2] = 0.f; ap[3] = 0.f;
#pragma unroll
      for (int kh = 0; kh < 2; kh++) {
        short8 efr = *(const short8*)(&lE[pr * 72 + kh * 32 + q4 * 8]);
        ap = MFMA16(efr, qsf[kh], ap);
      }
      *(f32x4*)(&Pw[l15 * 84 + pt * 16 + q4 * 4]) = ap;
    }

    __asm__ volatile("s_waitcnt lgkmcnt(0)" ::: "memory");
    __builtin_amdgcn_sched_barrier(0);   // rule #18: pin ops after the drain
    // srel(u=l15, v=ct*16+q4*4+rg) = Ps[l15][v + 15 - l15]
    const int rbase = l15 * 83 + q4 * 4 + 15;
    s16x4 bq[4];
#pragma unroll
    for (int ct = 0; ct < 4; ct++) {
      float pv[4];
#pragma unroll
      for (int rg = 0; rg < 4; rg++) {
        float s = accS[ct][rg] + Pw[rbase + ct * 16 + rg];
        if (last && (ct * 16 + q4 * 4 + rg) > Tm) s = -1e30f;
        float p = exp2f(s);
        l4[rg] += p;
        pv[rg] = p;
      }
      bq[ct] = pk4(pv[0], pv[1], pv[2], pv[3]);
    }
    __asm__ volatile("" ::: "memory");
    // ---- O^T += V^T P^T (V frags from registers; covered by softmax) ----
#pragma unroll
    for (int dt = 0; dt < 4; dt++)
#pragma unroll
      for (int ks = 0; ks < 4; ks++) {
        s16x4 vfr = (ks & 1) ? hi4(vf[dt * 2 + (ks >> 1)])
                             : lo4(vf[dt * 2 + (ks >> 1)]);
        accO[dt] = mfma16x16(vfr, bq[ks], accO[dt]);
      }
  };

  // ---- init: fill phys [0,128) = E rows ebase0+[0,128); stage C(1) regs ----
  for (int i = 0; i < 4; i++) {
    int cc = t + i * 256;
    int s = cc >> 3, c8 = (cc & 7) * 8;
    *(f32x4*)(&lE[s * 72 + c8]) =
        *(const f32x4*)(Eh + (size_t)(ebase0 + s) * HDc + c8);
  }
  f32x4 pE0, pE1;
  for (int rg = 0; rg < 4; rg++) { pE0[rg] = 0.f; pE1[rg] = 0.f; }
  if (qi >= 1) {   // C(1) rows = ebase0+128+[0,64), max 2112 < EStride
    pE0 = *(const f32x4*)(Eh + (size_t)(ebase0 + 128 + sr) * HDc + sc8);
    pE1 = *(const f32x4*)(Eh + (size_t)(ebase0 + 128 + sr2) * HDc + sc8);
  }

  // ---- main loop: ONE barrier per step ----
  int basej = 0;                                   // (64*j) % 192
  for (int j = 0; j < qi; j++) {
    __syncthreads();
    int pbase = basej + 128; if (pbase >= 192) pbase -= 192;
    *(f32x4*)(&lE[(pbase + sr) * 72 + sc8])  = pE0;   // write C(j+1)
    *(f32x4*)(&lE[(pbase + sr2) * 72 + sc8]) = pE1;
    if (j + 2 <= qi) {                                // stage C(j+2)
      const int ebn2 = ebase0 + 64 * j + 192;         // max 2112 < EStride
      pE0 = *(const f32x4*)(Eh + (size_t)(ebn2 + sr) * HDc + sc8);
      pE1 = *(const f32x4*)(Eh + (size_t)(ebn2 + sr2) * HDc + sc8);
    }
    body(j, basej, false, true);
    basej += 64; if (basej >= 192) basej -= 192;
  }

  // ---- peeled final (masked) step ----
  __syncthreads();
  body(qi, basej, true, false);

  // ---- epilogue: reduce l across q4 groups, b64 stores ----
  float l_p = (l4[0] + l4[1]) + (l4[2] + l4[3]);
  float l2 = l_p + __shfl_xor(l_p, 16);
  float lt = l2 + __shfl_xor(l2, 32);
  float inv = 1.f / lt;
  {
    int r = rw + l15;
    u16t* dst = AO + (size_t)(b * Nc + r) * Dc + h * HDc + q4 * 4;
    for (int dt = 0; dt < 4; dt++) {
      s16x4 o = pk4(accO[dt][0] * inv, accO[dt][1] * inv,
                    accO[dt][2] * inv, accO[dt][3] * inv);
      *(s16x4*)(dst + dt * 16) = o;
    }
  }
}

// ---------------- host ----------------
extern "C" void kernel_launch(void* const* d_in, const int* in_sizes, int n_in,
                              void* d_out, int out_size, void* d_ws, size_t ws_size,
                              hipStream_t stream) {
  (void)in_sizes; (void)n_in; (void)out_size; (void)ws_size;
  const float* x   = (const float*)d_in[0];
  const float* Wq  = (const float*)d_in[1];
  const float* Wk  = (const float*)d_in[2];
  const float* Wv  = (const float*)d_in[3];
  const float* Wp  = (const float*)d_in[4];
  const float* bp  = (const float*)d_in[5];
  const float* rel = (const float*)d_in[6];
  float* out = (float*)d_out;

  char* ws = (char*)d_ws;
  u16t* xb  = (u16t*)(ws);
  u16t* wqb = (u16t*)(ws + 8388608);
  u16t* wkb = (u16t*)(ws + 10485760);
  u16t* wvb = (u16t*)(ws + 12582912);
  u16t* wpb = (u16t*)(ws + 14680064);
  u16t* Eb  = (u16t*)(ws + 16777216);   // 16*2128*64*2 = 4358144 B
  u16t* Qb  = (u16t*)(ws + 21233664);
  u16t* Kb  = (u16t*)(ws + 29622272);
  u16t* Vtb = (u16t*)(ws + 38010880);
  u16t* AOb = (u16t*)(ws + 46399488);

  cvt_all<<<10320, 256, 0, stream>>>(x, Wq, Wk, Wv, Wp, rel,
                                     xb, wqb, wkb, wvb, wpb, Eb);
  gemm_qkv<<<dim3(32, 24), 256, 0, stream>>>(xb, wqb, wkb, wvb, Qb, Kb, Vtb);
  attn<<<dim3(1024), 256, 0, stream>>>(Qb, Kb, Vtb, Eb, AOb);
  gemm_proj<<<dim3(64, 16), 256, 0, stream>>>(AOb, wpb, out, bp);
}

// Round 16
// 194.383 us; speedup vs baseline: 5.9066x; 1.0255x over previous
//
#include <hip/hip_runtime.h>

typedef __attribute__((ext_vector_type(8))) short short8;
typedef __attribute__((ext_vector_type(4))) short s16x4;
typedef __attribute__((ext_vector_type(4))) float f32x4;
typedef unsigned short u16t;
typedef unsigned int u32t;

#define MFMA16(a,b,c) __builtin_amdgcn_mfma_f32_16x16x32_bf16((a),(b),(c),0,0,0)

__device__ __forceinline__ f32x4 mfma16x16(s16x4 a, s16x4 b, f32x4 c) {
#if __has_builtin(__builtin_amdgcn_mfma_f32_16x16x16bf16_1k)
  return __builtin_amdgcn_mfma_f32_16x16x16bf16_1k(a, b, c, 0, 0, 0);
#else
  __asm__("v_mfma_f32_16x16x16_bf16 %0, %1, %2, %0" : "+v"(c) : "v"(a), "v"(b));
  return c;
#endif
}

constexpr int Bc = 2, Nc = 2048, Dc = 1024, NHc = 16, HDc = 64;
constexpr int EStride = Nc + 80;   // E rows per head incl. zero pad

__device__ __forceinline__ u16t f2bf(float f) {   // RTN (cold paths)
  union { float f; u32t u; } v; v.f = f;
  u32t r = v.u + 0x7FFFu + ((v.u >> 16) & 1u);
  return (u16t)(r >> 16);
}
// pack two floats -> bf16x2; HW packed cvt when available
#if __has_builtin(__builtin_amdgcn_cvt_pk_bf16_f32)
__device__ __forceinline__ u32t pk2(float a, float b) {
  auto r = __builtin_amdgcn_cvt_pk_bf16_f32(a, b);
  return __builtin_bit_cast(u32t, r);
}
#else
__device__ __forceinline__ u32t pk2(float a, float b) {
  u32t ua = __builtin_bit_cast(u32t, a);
  u32t ub = __builtin_bit_cast(u32t, b);
  return ((ua + 0x8000u) >> 16) | ((ub + 0x8000u) & 0xFFFF0000u);
}
#endif
__device__ __forceinline__ s16x4 pk4(float a, float b, float c, float d) {
  union { u32t u[2]; s16x4 s; } r;
  r.u[0] = pk2(a, b); r.u[1] = pk2(c, d);
  return r.s;
}

__device__ __forceinline__ s16x4 lo4(short8 v) {
  return __builtin_shufflevector(v, v, 0, 1, 2, 3);
}
__device__ __forceinline__ s16x4 hi4(short8 v) {
  return __builtin_shufflevector(v, v, 4, 5, 6, 7);
}

// async global->LDS, 16B per lane
__device__ __forceinline__ void gld16(const u16t* g, u16t* l) {
  __builtin_amdgcn_global_load_lds(
      (const __attribute__((address_space(1))) unsigned int*)(g),
      (__attribute__((address_space(3))) unsigned int*)(l), 16, 0, 0);
}

// ---------------- fused conversion: x, 4 weights, E remap + zero pad ----------------
__device__ __forceinline__ void cvt4(const float* s, u16t* d) {
  f32x4 v = *(const f32x4*)s;
  u32t* dp = (u32t*)d;
  dp[0] = pk2(v[0], v[1]); dp[1] = pk2(v[2], v[3]);
}

__global__ __launch_bounds__(256) void cvt_all(
    const float* __restrict__ x, const float* __restrict__ wq,
    const float* __restrict__ wk, const float* __restrict__ wv,
    const float* __restrict__ wp, const float* __restrict__ rel,
    u16t* __restrict__ xb, u16t* __restrict__ wqb, u16t* __restrict__ wkb,
    u16t* __restrict__ wvb, u16t* __restrict__ wpb, u16t* __restrict__ Eb) {
  int i = blockIdx.x * 256 + threadIdx.x;
  if (i < 1048576) {                        // x
    cvt4(x + (size_t)i * 4, xb + (size_t)i * 4);
  } else if (i < 2097152) {                 // weights
    int r = i - 1048576;
    int w = r >> 18;
    int k = (r & 262143) * 4;
    const float* s = (w == 0) ? wq : (w == 1) ? wk : (w == 2) ? wv : wp;
    u16t* d = (w == 0) ? wqb : (w == 1) ? wkb : (w == 2) ? wvb : wpb;
    cvt4(s + k, d + k);
  } else if (i < 2621440) {                 // E remap to [h][m][hd]
    int r = i - 2097152;
    int flat = r * 4;
    int h = flat >> 17;
    int rem = flat & 131071;
    int m = rem >> 6, d = rem & 63;
    cvt4(rel + (size_t)m * Dc + h * HDc + d,
         Eb + ((size_t)h * EStride + m) * HDc + d);
  } else {                                  // zero pad rows [Nc, Nc+80)
    int r = i - 2621440;
    int flat = r * 4;
    int h = flat / 5120;
    int rem = flat - h * 5120;
    int pr = rem >> 6, d = rem & 63;
    u32t* dp = (u32t*)(Eb + ((size_t)h * EStride + Nc + pr) * HDc + d);
    dp[0] = 0; dp[1] = 0;
  }
}

// ---------------- fused QKV GEMM: out = x @ W^T ----------------
// ROUND-6 VERSION (38.5us isolated via r6<->r8 totals). Q row-major
// pre-scaled by 0.125*log2(e); K and V in attn MFMA FRAG layout.
// Session note: the r7/r8 rework (operand swap + which-branch in the K-loop)
// doubled this kernel; do not re-derive without isolating the mechanism.
__global__ __launch_bounds__(256, 3) void gemm_qkv(const u16t* __restrict__ A,
    const u16t* __restrict__ Wq, const u16t* __restrict__ Wk,
    const u16t* __restrict__ Wv, u16t* __restrict__ Qb,
    u16t* __restrict__ Kb, u16t* __restrict__ Vt) {
  __shared__ u16t lA[128 * 32];   // unpadded: required by global_load_lds
  __shared__ u16t lB[128 * 32];
  const int y = blockIdx.y, which = y >> 3;
  const u16t* W = (which == 0) ? Wq : (which == 1) ? Wk : Wv;
  const float sc = 0.18033688011112042f;    // Q only
  const int m0 = blockIdx.x * 128, n0 = (y & 7) * 128;
  const int t = threadIdx.x, wave = t >> 6, lane = t & 63;
  const int l15 = lane & 15, q4 = lane >> 4, wm = wave & 1, wn = wave >> 1;
  const int srow = wave * 16 + (lane >> 2);
  const int scol = (lane & 3) * 8;

  f32x4 acc[4][4];
  for (int i = 0; i < 4; i++)
    for (int j = 0; j < 4; j++)
      for (int r = 0; r < 4; r++) acc[i][j][r] = 0.f;

  for (int k0 = 0; k0 < Dc; k0 += 32) {
    __syncthreads();
    for (int r = 0; r < 2; r++) {
      int row = srow + r * 64;
      gld16(A + (size_t)(m0 + row) * Dc + k0 + scol, lA + wave * 512 + r * 2048);
      gld16(W + (size_t)(n0 + row) * Dc + k0 + scol, lB + wave * 512 + r * 2048);
    }
    __syncthreads();
    short8 af[4], bf[4];
    for (int i = 0; i < 4; i++) {
      af[i] = *(const short8*)(&lA[(wm * 64 + i * 16 + l15) * 32 + q4 * 8]);
      bf[i] = *(const short8*)(&lB[(wn * 64 + i * 16 + l15) * 32 + q4 * 8]);
    }
    for (int mi = 0; mi < 4; mi++)
      for (int ni = 0; ni < 4; ni++)
        acc[mi][ni] = MFMA16(af[mi], bf[ni], acc[mi][ni]);
  }

  if (which == 0) {
    for (int mi = 0; mi < 4; mi++)
      for (int ni = 0; ni < 4; ni++)
        for (int rg = 0; rg < 4; rg++) {
          int gm = m0 + wm * 64 + mi * 16 + q4 * 4 + rg;
          int gn = n0 + wn * 64 + ni * 16 + l15;
          int b = gm >> 11, n = gm & 2047, h = gn >> 6, hd = gn & 63;
          Qb[(((size_t)(b * NHc + h) * Nc + n) * HDc) + hd] =
              f2bf(acc[mi][ni][rg] * sc);
        }
  } else if (which == 1) {
    for (int mi = 0; mi < 4; mi++)
      for (int ni = 0; ni < 4; ni++)
        for (int rg = 0; rg < 4; rg++) {
          int gm = m0 + wm * 64 + mi * 16 + q4 * 4 + rg;
          int gn = n0 + wn * 64 + ni * 16 + l15;
          int b = gm >> 11, n = gm & 2047, h = gn >> 6, hd = gn & 63;
          size_t off = (size_t)(b * NHc + h) * Nc * HDc
                     + (size_t)(n >> 6) * 4096
                     + ((((n >> 4) & 3) * 2 + (hd >> 5)) * 512)
                     + (((hd >> 3) & 3) * 128) + ((n & 15) * 8) + (hd & 7);
          Kb[off] = f2bf(acc[mi][ni][rg]);
        }
  } else {
    // V: rows of acc (rg) are consecutive n -> contiguous 8B in frag layout.
    for (int mi = 0; mi < 4; mi++)
      for (int ni = 0; ni < 4; ni++) {
        int gm = m0 + wm * 64 + mi * 16 + q4 * 4;       // n base (rg=0)
        int gn = n0 + wn * 64 + ni * 16 + l15;
        int b = gm >> 11, n = gm & 2047, h = gn >> 6, hd = gn & 63;
        s16x4 pkv = pk4(acc[mi][ni][0], acc[mi][ni][1],
                        acc[mi][ni][2], acc[mi][ni][3]);
        size_t off = (size_t)(b * NHc + h) * Nc * HDc
                   + (size_t)(n >> 6) * 4096
                   + (((hd >> 4) * 2 + ((n >> 5) & 1)) * 512)
                   + (((n >> 2) & 3) * 128) + ((hd & 15) * 8)
                   + (((n >> 4) & 1) * 4);
        *(s16x4*)(&Vt[off]) = pkv;
      }
  }
}

// ---------------- output projection GEMM: out = AO @ Wp^T + bp (fp32) ----------------
// ROUND-16: BK=64 (was 32) -> 16 K-steps instead of 32. proj is the last
// unmeasured kernel (sat under attn's top-5 cutoff all session; accounting
// bounds it 25-63us). r9 proved it's NOT occupancy-bound (4/CU neutral);
// theory: chain-bound on 32x (2 barriers + vmcnt drain + only 4 MFMA).
// BK=64 halves the barrier/drain count, doubles per-step compute (8 MFMA).
// Two separate [64][32] half-K buffers preserve the exact proven LDS layout
// (a fused [64][64] would add a stride-128B bank conflict). LDS 16KB, 4/CU.
__global__ __launch_bounds__(256, 4) void gemm_proj(const u16t* __restrict__ A,
    const u16t* __restrict__ W, float* __restrict__ outf,
    const float* __restrict__ bias) {
  __shared__ u16t lA[2][64 * 32];
  __shared__ u16t lB[2][64 * 32];
  const int m0 = blockIdx.x * 64, n0 = blockIdx.y * 64;
  const int t = threadIdx.x, wave = t >> 6, lane = t & 63;
  const int l15 = lane & 15, q4 = lane >> 4, wm = wave & 1, wn = wave >> 1;
  const int srow = t >> 2;            // 256 threads cover 64 rows x 32 cols
  const int scol = (t & 3) * 8;

  f32x4 acc[2][2];
  for (int i = 0; i < 2; i++)
    for (int j = 0; j < 2; j++)
      for (int r = 0; r < 4; r++) acc[i][j][r] = 0.f;

  for (int k0 = 0; k0 < Dc; k0 += 64) {
    __syncthreads();
    for (int h = 0; h < 2; h++) {
      gld16(A + (size_t)(m0 + srow) * Dc + k0 + h * 32 + scol,
            &lA[h][0] + wave * 512);
      gld16(W + (size_t)(n0 + srow) * Dc + k0 + h * 32 + scol,
            &lB[h][0] + wave * 512);
    }
    __syncthreads();
#pragma unroll
    for (int h = 0; h < 2; h++) {
      short8 af[2], bf[2];
      for (int i = 0; i < 2; i++) {
        af[i] = *(const short8*)(&lA[h][(wm * 32 + i * 16 + l15) * 32 + q4 * 8]);
        bf[i] = *(const short8*)(&lB[h][(wn * 32 + i * 16 + l15) * 32 + q4 * 8]);
      }
      for (int mi = 0; mi < 2; mi++)
        for (int ni = 0; ni < 2; ni++)
          acc[mi][ni] = MFMA16(af[mi], bf[ni], acc[mi][ni]);
    }
  }

  for (int mi = 0; mi < 2; mi++)
    for (int ni = 0; ni < 2; ni++)
      for (int rg = 0; rg < 4; rg++) {
        int gm = m0 + wm * 32 + mi * 16 + q4 * 4 + rg;
        int gn = n0 + wn * 32 + ni * 16 + l15;
        outf[(size_t)gm * Dc + gn] = acc[mi][ni][rg] + bias[gn];
      }
}

// ---------------- fused causal attention (transposed compute) ----------------
// Round-6/9 version (best measured: 63.6us). Tri-buffered lE (one barrier
// per step), frag-layout K/V direct from global (L1 broadcast), K prefetch
// one step ahead, longest-first tiles + hardware backfill.
__global__ __launch_bounds__(256, 3) void attn(const u16t* __restrict__ Qb,
                                               const u16t* __restrict__ Kb,
                                               const u16t* __restrict__ Vt,
                                               const u16t* __restrict__ Eb,
                                               u16t* __restrict__ AO) {
  __shared__ u16t lE[192 * 72];      // 27648 B tri-buffer
  __shared__ float Ps[4][16 * 84];   // 21504 B wave-private fp32 srel scratch

  const int bid = blockIdx.x;
  const int qi = 31 - (bid >> 5);    // longest tiles dispatched first
  const int bh = bid & 31;
  const int b = bh >> 4, h = bh & 15;

  const u16t* Qh = Qb + (size_t)(b * NHc + h) * Nc * HDc;
  const u16t* Kh = Kb + (size_t)(b * NHc + h) * Nc * HDc;  // frag layout
  const u16t* Vh = Vt + (size_t)(b * NHc + h) * Nc * HDc;  // frag layout
  const u16t* Eh = Eb + (size_t)h * EStride * HDc;

  const int t = threadIdx.x, wave = t >> 6, lane = t & 63, l15 = lane & 15, q4 = lane >> 4;
  const int tbase = (3 - wave) * 16;
  const int Tm = wave * 16 + l15;    // causal threshold for the final step
  float* Pw = Ps[wave];

  const int sr = t >> 3, sc8 = (t & 7) * 8;
  const int sr2 = sr + 32;

  const int r0 = qi * 64;
  const int rw = r0 + wave * 16;
  const int ebase0 = Nc - 63 - r0;

  short8 qf[2], qsf[2];
  {
    int r = rw + l15;
    int rs = r - 1; if (rs < 0) rs = 0;
    for (int kh = 0; kh < 2; kh++) {
      qf[kh]  = *(const short8*)(Qh + (size_t)r * HDc + kh * 32 + q4 * 8);
      qsf[kh] = *(const short8*)(Qh + (size_t)rs * HDc + kh * 32 + q4 * 8);
    }
  }

  f32x4 accO[4];
  f32x4 l4;                          // 4-way partial row-sums
  for (int rg = 0; rg < 4; rg++) l4[rg] = 0.f;
  for (int dt = 0; dt < 4; dt++)
    for (int rg = 0; rg < 4; rg++) accO[dt][rg] = 0.f;

  // K fragments for the CURRENT step (prefetched one step ahead)
  short8 kf[8];
#pragma unroll
  for (int i = 0; i < 8; i++)
    kf[i] = *(const short8*)(Kh + i * 512 + lane * 8);

  // step body. basej = (64*j)%192. pf: prefetch K for step j+1.
  auto body = [&](int j, int basej, bool last, bool pf) {
    const u16t* Vj = Vh + (size_t)j * 4096;
    short8 vf[8];
#pragma unroll
    for (int i = 0; i < 8; i++)
      vf[i] = *(const short8*)(Vj + i * 512 + lane * 8);

    // ---- S^T = MFMA(K, Q): operands already resident (prefetched) ----
    f32x4 accS[4];
    for (int ct = 0; ct < 4; ct++)
      for (int rg = 0; rg < 4; rg++) accS[ct][rg] = 0.f;
#pragma unroll
    for (int kh = 0; kh < 2; kh++)
#pragma unroll
      for (int ct = 0; ct < 4; ct++)
        accS[ct] = MFMA16(kf[ct * 2 + kh], qf[kh], accS[ct]);

    // ---- prefetch K for next step (kf's only consumer was S above) ----
    if (pf) {
      const u16t* Kn = Kh + (size_t)(j + 1) * 4096;
#pragma unroll
      for (int i = 0; i < 8; i++)
        kf[i] = *(const short8*)(Kn + i * 512 + lane * 8);
    }

    // ---- Pe^T = MFMA(E, Qs) from LDS tri-buffer; write Ps per tile ----
    const int pb = basej + tbase + l15;
#pragma unroll
    for (int pt = 0; pt < 5; pt++) {
      int pr = pb + pt * 16; if (pr >= 192) pr -= 192;
      f32x4 ap;
      ap[0] = 0.f; ap[1] = 0.f; ap[2] = 0.f; ap[3] = 0.f;
#pragma unroll
      for (int kh = 0; kh < 2; kh++) {
        short8 efr = *(const short8*)(&lE[pr * 72 + kh * 32 + q4 * 8]);
        ap = MFMA16(efr, qsf[kh], ap);
      }
      *(f32x4*)(&Pw[l15 * 84 + pt * 16 + q4 * 4]) = ap;
    }

    __asm__ volatile("s_waitcnt lgkmcnt(0)" ::: "memory");
    __builtin_amdgcn_sched_barrier(0);   // rule #18: pin ops after the drain
    // srel(u=l15, v=ct*16+q4*4+rg) = Ps[l15][v + 15 - l15]
    const int rbase = l15 * 83 + q4 * 4 + 15;
    s16x4 bq[4];
#pragma unroll
    for (int ct = 0; ct < 4; ct++) {
      float pv[4];
#pragma unroll
      for (int rg = 0; rg < 4; rg++) {
        float s = accS[ct][rg] + Pw[rbase + ct * 16 + rg];
        if (last && (ct * 16 + q4 * 4 + rg) > Tm) s = -1e30f;
        float p = exp2f(s);
        l4[rg] += p;
        pv[rg] = p;
      }
      bq[ct] = pk4(pv[0], pv[1], pv[2], pv[3]);
    }
    __asm__ volatile("" ::: "memory");
    // ---- O^T += V^T P^T (V frags from registers; covered by softmax) ----
#pragma unroll
    for (int dt = 0; dt < 4; dt++)
#pragma unroll
      for (int ks = 0; ks < 4; ks++) {
        s16x4 vfr = (ks & 1) ? hi4(vf[dt * 2 + (ks >> 1)])
                             : lo4(vf[dt * 2 + (ks >> 1)]);
        accO[dt] = mfma16x16(vfr, bq[ks], accO[dt]);
      }
  };

  // ---- init: fill phys [0,128) = E rows ebase0+[0,128); stage C(1) regs ----
  for (int i = 0; i < 4; i++) {
    int cc = t + i * 256;
    int s = cc >> 3, c8 = (cc & 7) * 8;
    *(f32x4*)(&lE[s * 72 + c8]) =
        *(const f32x4*)(Eh + (size_t)(ebase0 + s) * HDc + c8);
  }
  f32x4 pE0, pE1;
  for (int rg = 0; rg < 4; rg++) { pE0[rg] = 0.f; pE1[rg] = 0.f; }
  if (qi >= 1) {   // C(1) rows = ebase0+128+[0,64), max 2112 < EStride
    pE0 = *(const f32x4*)(Eh + (size_t)(ebase0 + 128 + sr) * HDc + sc8);
    pE1 = *(const f32x4*)(Eh + (size_t)(ebase0 + 128 + sr2) * HDc + sc8);
  }

  // ---- main loop: ONE barrier per step ----
  int basej = 0;                                   // (64*j) % 192
  for (int j = 0; j < qi; j++) {
    __syncthreads();
    int pbase = basej + 128; if (pbase >= 192) pbase -= 192;
    *(f32x4*)(&lE[(pbase + sr) * 72 + sc8])  = pE0;   // write C(j+1)
    *(f32x4*)(&lE[(pbase + sr2) * 72 + sc8]) = pE1;
    if (j + 2 <= qi) {                                // stage C(j+2)
      const int ebn2 = ebase0 + 64 * j + 192;         // max 2112 < EStride
      pE0 = *(const f32x4*)(Eh + (size_t)(ebn2 + sr) * HDc + sc8);
      pE1 = *(const f32x4*)(Eh + (size_t)(ebn2 + sr2) * HDc + sc8);
    }
    body(j, basej, false, true);
    basej += 64; if (basej >= 192) basej -= 192;
  }

  // ---- peeled final (masked) step ----
  __syncthreads();
  body(qi, basej, true, false);

  // ---- epilogue: reduce l across q4 groups, b64 stores ----
  float l_p = (l4[0] + l4[1]) + (l4[2] + l4[3]);
  float l2 = l_p + __shfl_xor(l_p, 16);
  float lt = l2 + __shfl_xor(l2, 32);
  float inv = 1.f / lt;
  {
    int r = rw + l15;
    u16t* dst = AO + (size_t)(b * Nc + r) * Dc + h * HDc + q4 * 4;
    for (int dt = 0; dt < 4; dt++) {
      s16x4 o = pk4(accO[dt][0] * inv, accO[dt][1] * inv,
                    accO[dt][2] * inv, accO[dt][3] * inv);
      *(s16x4*)(dst + dt * 16) = o;
    }
  }
}

// ---------------- host ----------------
extern "C" void kernel_launch(void* const* d_in, const int* in_sizes, int n_in,
                              void* d_out, int out_size, void* d_ws, size_t ws_size,
                              hipStream_t stream) {
  (void)in_sizes; (void)n_in; (void)out_size; (void)ws_size;
  const float* x   = (const float*)d_in[0];
  const float* Wq  = (const float*)d_in[1];
  const float* Wk  = (const float*)d_in[2];
  const float* Wv  = (const float*)d_in[3];
  const float* Wp  = (const float*)d_in[4];
  const float* bp  = (const float*)d_in[5];
  const float* rel = (const float*)d_in[6];
  float* out = (float*)d_out;

  char* ws = (char*)d_ws;
  u16t* xb  = (u16t*)(ws);
  u16t* wqb = (u16t*)(ws + 8388608);
  u16t* wkb = (u16t*)(ws + 10485760);
  u16t* wvb = (u16t*)(ws + 12582912);
  u16t* wpb = (u16t*)(ws + 14680064);
  u16t* Eb  = (u16t*)(ws + 16777216);   // 16*2128*64*2 = 4358144 B
  u16t* Qb  = (u16t*)(ws + 21233664);
  u16t* Kb  = (u16t*)(ws + 29622272);
  u16t* Vtb = (u16t*)(ws + 38010880);
  u16t* AOb = (u16t*)(ws + 46399488);

  cvt_all<<<10320, 256, 0, stream>>>(x, Wq, Wk, Wv, Wp, rel,
                                     xb, wqb, wkb, wvb, wpb, Eb);
  gemm_qkv<<<dim3(32, 24), 256, 0, stream>>>(xb, wqb, wkb, wvb, Qb, Kb, Vtb);
  attn<<<dim3(1024), 256, 0, stream>>>(Qb, Kb, Vtb, Eb, AOb);
  gemm_proj<<<dim3(64, 16), 256, 0, stream>>>(AOb, wpb, out, bp);
}